// Round 5
// baseline (2301.778 us; speedup 1.0000x reference)
//
#include <hip/hip_runtime.h>
#include <cmath>

typedef __attribute__((ext_vector_type(8))) short bf16x8;
typedef __attribute__((ext_vector_type(4))) float f32x4;

#define LSTM_BLOCKS 256

__device__ __forceinline__ unsigned short f2b(float x) {
  unsigned u = __builtin_bit_cast(unsigned, x);
  u += 0x7fffu + ((u >> 16) & 1u);
  return (unsigned short)(u >> 16);
}

__device__ __forceinline__ void gload16(const void* g, void* l) {
  __builtin_amdgcn_global_load_lds(
      (const __attribute__((address_space(1))) void*)g,
      (__attribute__((address_space(3))) void*)l, 16, 0, 0);
}

// ============================================================================
// Stage 1: fused conv1 + relu + maxpool2x2 + conv2 + relu + spatial-sum.
// Tile = 32x16 pooled px: s_p1 41 KB, LDS ~61 KB -> 2 blocks/CU. Grid 2048.
// ============================================================================
__global__ __launch_bounds__(512) void k_conv(
    const float* __restrict__ mask, const float* __restrict__ w1,
    const float* __restrict__ b1, const float* __restrict__ w2,
    const float* __restrict__ b2, float* __restrict__ part)
{
  __shared__ float s_p1[16][18 * 36];
  __shared__ float s_w1[144];
  __shared__ float s_b1[16];
  __shared__ float s_w2[4608];
  __shared__ float s_b2[32];

  const int tid = threadIdx.x;
  const int b = blockIdx.x >> 5;
  const int tile = blockIdx.x & 31;
  const int px0 = (tile & 3) * 32, py0 = (tile >> 2) * 16;
  const float* mb = mask + (size_t)b * 65536;

  for (int i = tid; i < 144; i += 512) s_w1[i] = w1[i];
  for (int i = tid; i < 4608; i += 512) s_w2[i] = w2[i];
  if (tid < 16) s_b1[tid] = b1[tid];
  if (tid < 32) s_b2[tid] = b2[tid];
  __syncthreads();

  // conv1 + relu + 2x2 maxpool into s_p1 (18x34 incl. halo), relu folded in.
  for (int idx = tid; idx < 18 * 34; idx += 512) {
    int ly = idx / 34, lx = idx - ly * 34;
    int py = py0 - 1 + ly, px = px0 - 1 + lx;
    if (py < 0 || py >= 128 || px < 0 || px >= 128) {
      for (int o = 0; o < 16; o++) s_p1[o][ly * 36 + lx] = 0.f;
    } else {
      float patch[4][4];
      int gy0 = 2 * py - 1, gx0 = 2 * px - 1;
#pragma unroll
      for (int i = 0; i < 4; i++) {
        int gy = gy0 + i;
        bool yok = (gy >= 0 && gy < 256);
#pragma unroll
        for (int j = 0; j < 4; j++) {
          int gx = gx0 + j;
          patch[i][j] = (yok && gx >= 0 && gx < 256) ? mb[gy * 256 + gx] : 0.f;
        }
      }
      for (int o = 0; o < 16; o++) {
        float m = 0.f;
#pragma unroll
        for (int dy = 0; dy < 2; dy++)
#pragma unroll
          for (int dx = 0; dx < 2; dx++) {
            float v = s_b1[o];
#pragma unroll
            for (int ky = 0; ky < 3; ky++)
#pragma unroll
              for (int kx = 0; kx < 3; kx++)
                v = fmaf(patch[dy + ky][dx + kx], s_w1[o * 9 + ky * 3 + kx], v);
            m = fmaxf(m, v);
          }
        s_p1[o][ly * 36 + lx] = m;
      }
    }
  }
  __syncthreads();

  // conv2 (3x3, 16->32ch) + relu + tile-sum.
  const int ocg = tid >> 6;
  const int sp = tid & 63;
  const int sx = (sp & 7) * 4, sy = (sp >> 3) * 2;
  float acc[4][8];
#pragma unroll
  for (int a = 0; a < 4; a++)
#pragma unroll
    for (int q = 0; q < 8; q++) acc[a][q] = 0.f;

  for (int ic = 0; ic < 16; ic++) {
    float p[4][6];
#pragma unroll
    for (int i = 0; i < 4; i++) {
      const float* row = &s_p1[ic][(sy + i) * 36 + sx];
#pragma unroll
      for (int j = 0; j < 6; j++) p[i][j] = row[j];
    }
#pragma unroll
    for (int o4 = 0; o4 < 4; o4++) {
      const int oc = ocg * 4 + o4;
      const float* w = &s_w2[(oc * 16 + ic) * 9];
      float w00 = w[0], w01 = w[1], w02 = w[2];
      float w10 = w[3], w11 = w[4], w12 = w[5];
      float w20 = w[6], w21 = w[7], w22 = w[8];
#pragma unroll
      for (int y = 0; y < 2; y++)
#pragma unroll
        for (int x = 0; x < 4; x++) {
          float s = acc[o4][y * 4 + x];
          s = fmaf(p[y][x], w00, s);
          s = fmaf(p[y][x + 1], w01, s);
          s = fmaf(p[y][x + 2], w02, s);
          s = fmaf(p[y + 1][x], w10, s);
          s = fmaf(p[y + 1][x + 1], w11, s);
          s = fmaf(p[y + 1][x + 2], w12, s);
          s = fmaf(p[y + 2][x], w20, s);
          s = fmaf(p[y + 2][x + 1], w21, s);
          s = fmaf(p[y + 2][x + 2], w22, s);
          acc[o4][y * 4 + x] = s;
        }
    }
  }

  const int lane = tid & 63;
#pragma unroll
  for (int o4 = 0; o4 < 4; o4++) {
    float bv = s_b2[ocg * 4 + o4];
    float s = 0.f;
#pragma unroll
    for (int q = 0; q < 8; q++) s += fmaxf(acc[o4][q] + bv, 0.f);
    for (int off = 32; off > 0; off >>= 1) s += __shfl_down(s, off, 64);
    if (lane == 0) part[(b * 32 + tile) * 32 + ocg * 4 + o4] = s;
  }
}

// ============================================================================
// Stage 2a: tile partials -> pooled mean -> h0 GEMM (K=32). h0 -> hbuf[0].
// ============================================================================
__global__ __launch_bounds__(256) void k_pool_h0(
    const float* __restrict__ part, const float* __restrict__ feat_w,
    const float* __restrict__ feat_b, float* __restrict__ h0)
{
  const int b = blockIdx.x, tid = threadIdx.x;
  __shared__ float pl[32];
  if (tid < 32) {
    float s = 0.f;
    for (int t = 0; t < 32; t++) s += part[(b * 32 + t) * 32 + tid];
    pl[tid] = s * (1.0f / 16384.0f);
  }
  __syncthreads();
  for (int j = tid; j < 512; j += 256) {
    float acc = feat_b[j];
    const float* w = feat_w + j * 32;
#pragma unroll
    for (int ic = 0; ic < 32; ic++) acc = fmaf(pl[ic], w[ic], acc);
    h0[b * 512 + j] = acc;
  }
}

// ============================================================================
// Stage 2b: ctx = h0 @ ctx_w.T + ctx_b.
// ============================================================================
__global__ __launch_bounds__(256) void k_ctx(
    const float* __restrict__ h0, const float* __restrict__ ctx_w,
    const float* __restrict__ ctx_b, float* __restrict__ ctx)
{
  const int b = blockIdx.x, tid = threadIdx.x;
  __shared__ float hs[512];
  for (int k = tid; k < 512; k += 256) hs[k] = h0[b * 512 + k];
  __syncthreads();
  for (int j = tid; j < 512; j += 256) {
    const float* w = ctx_w + (size_t)j * 512;
    float s0 = 0.f, s1 = 0.f, s2 = 0.f, s3 = 0.f;
    for (int k = 0; k < 512; k += 4) {
      float4 w4 = *(const float4*)(w + k);
      s0 = fmaf(hs[k], w4.x, s0);
      s1 = fmaf(hs[k + 1], w4.y, s1);
      s2 = fmaf(hs[k + 2], w4.z, s2);
      s3 = fmaf(hs[k + 3], w4.w, s3);
    }
    ctx[b * 512 + j] = ctx_b[j] + ((s0 + s1) + (s2 + s3));
  }
}

// ============================================================================
// fp32 -> bf16 (RNE), 4 elems/thread.
// ============================================================================
__global__ __launch_bounds__(256) void k_f2b(
    const float* __restrict__ in, unsigned short* __restrict__ out, int n)
{
  int i = (blockIdx.x * 256 + threadIdx.x) * 4;
  if (i < n) {
    float4 v = *(const float4*)(in + i);
    unsigned lo = (unsigned)f2b(v.x) | ((unsigned)f2b(v.y) << 16);
    unsigned hi = (unsigned)f2b(v.z) | ((unsigned)f2b(v.w) << 16);
    *(uint2*)(out + i) = make_uint2(lo, hi);
  }
}

// ============================================================================
// Zero helpers (ws poisoned to 0xAA before timing; re-init every call).
// ============================================================================
__global__ __launch_bounds__(64) void k_zero(int* __restrict__ p) {
  p[threadIdx.x] = 0;
}
__global__ __launch_bounds__(256) void k_zero_f(float* __restrict__ p) {
  p[blockIdx.x * 256 + threadIdx.x] = 0.f;
}

// ============================================================================
// Stage 3a: A[(t*64+b)][k] = bf16(tok_emb[tok][k] + ctx[b][k])
// ============================================================================
__global__ __launch_bounds__(128) void k_build_A(
    const float* __restrict__ tok_emb, const int* __restrict__ tgt,
    const float* __restrict__ ctx, unsigned short* __restrict__ A)
{
  const int r = blockIdx.x;
  const int t = r >> 6, b = r & 63;
  const int tok = (t == 0) ? 4096 : tgt[b * 50 + (t - 1)];
  const int i = threadIdx.x * 4;
  float4 ev = *(const float4*)(tok_emb + (size_t)tok * 512 + i);
  float4 cv = *(const float4*)(ctx + b * 512 + i);
  unsigned lo = (unsigned)f2b(ev.x + cv.x) | ((unsigned)f2b(ev.y + cv.y) << 16);
  unsigned hi = (unsigned)f2b(ev.z + cv.z) | ((unsigned)f2b(ev.w + cv.w) << 16);
  *(uint2*)(A + (size_t)r * 512 + i) = make_uint2(lo, hi);
}

// ============================================================================
// bf16 MFMA GEMM (m97 structure): C(MxN) = A(Mx512) @ B(Nx512)^T + bias.
// MODE 0: xgates; C written TRANSPOSED as (t, gate-dd, b) = (50,2048,64).
// MODE 1: head; C remapped (t*64+b, v) -> (b*50+t, v).
// ============================================================================
template <int MODE>
__global__ __launch_bounds__(256) void k_gemm_mfma(
    const unsigned short* __restrict__ A, const unsigned short* __restrict__ B,
    const float* __restrict__ bias_a, const float* __restrict__ bias_b,
    float* __restrict__ C, int NB)
{
  __shared__ unsigned short sA[128 * 32];
  __shared__ unsigned short sB[128 * 32];
  const int tid = threadIdx.x;
  const int bx = blockIdx.x % NB, by = blockIdx.x / NB;
  const int lane = tid & 63, wv = tid >> 6;
  const int wr = wv >> 1, wc = wv & 1;
  const unsigned short* Ab = A + (size_t)by * 128 * 512;
  const unsigned short* Bb = B + (size_t)bx * 128 * 512;

  f32x4 acc[4][4];
#pragma unroll
  for (int m = 0; m < 4; m++)
#pragma unroll
    for (int n = 0; n < 4; n++) acc[m][n] = (f32x4){0.f, 0.f, 0.f, 0.f};

  const int r0 = tid >> 2, c0 = (tid & 3) * 8;
  const int idx1 = tid + 256;
  const int r1 = idx1 >> 2, c1 = (idx1 & 3) * 8;
  unsigned short* lA0 = sA + (size_t)wv * 512;
  unsigned short* lA1 = sA + 2048 + (size_t)wv * 512;
  unsigned short* lB0 = sB + (size_t)wv * 512;
  unsigned short* lB1 = sB + 2048 + (size_t)wv * 512;

  const int frow = lane & 15;
  const int foff = (lane >> 4) * 8;

  for (int kc = 0; kc < 512; kc += 32) {
    gload16(Ab + (size_t)r0 * 512 + kc + c0, lA0);
    gload16(Ab + (size_t)r1 * 512 + kc + c1, lA1);
    gload16(Bb + (size_t)r0 * 512 + kc + c0, lB0);
    gload16(Bb + (size_t)r1 * 512 + kc + c1, lB1);
    __syncthreads();

    bf16x8 af[4], bfr[4];
#pragma unroll
    for (int m = 0; m < 4; m++)
      af[m] = *(const bf16x8*)(sA + (wr * 64 + m * 16 + frow) * 32 + foff);
#pragma unroll
    for (int n = 0; n < 4; n++)
      bfr[n] = *(const bf16x8*)(sB + (wc * 64 + n * 16 + frow) * 32 + foff);
#pragma unroll
    for (int m = 0; m < 4; m++)
#pragma unroll
      for (int n = 0; n < 4; n++)
        acc[m][n] = __builtin_amdgcn_mfma_f32_16x16x32_bf16(
            af[m], bfr[n], acc[m][n], 0, 0, 0);
    __syncthreads();
  }

  // C/D layout (m91-verified): col = lane&15, row = (lane>>4)*4 + j
#pragma unroll
  for (int n = 0; n < 4; n++) {
    const int gc = bx * 128 + wc * 64 + n * 16 + (lane & 15);
    const float bv = (MODE == 0) ? (bias_a[gc] + bias_b[gc]) : bias_a[gc];
#pragma unroll
    for (int m = 0; m < 4; m++) {
      const int rb = by * 128 + wr * 64 + m * 16 + (lane >> 4) * 4;
#pragma unroll
      for (int j = 0; j < 4; j++) {
        const int r = rb + j;
        float v = acc[m][n][j] + bv;
        int t = r >> 6, bb = r & 63;
        if (MODE == 0) {
          C[(size_t)t * 131072 + (size_t)gc * 64 + bb] = v;
        } else {
          C[((size_t)bb * 50 + t) * 4096 + gc] = v;
        }
      }
    }
  }
}

// ============================================================================
// Stage 4 (primary): PERSISTENT LSTM — all 50 steps, ONE cooperative dispatch.
// Cooperative launch guarantees all 256 blocks co-resident (or the launch
// errors -> hang-proof). Block owns 2 hidden dims; w_hh staged to LDS once;
// cell state in registers; fence+atomic grid barrier per step.
// ============================================================================
__global__ __launch_bounds__(256) void k_lstm_all(
    const float* __restrict__ xgT,      // (50, 2048, 64) transposed xgates
    const float* __restrict__ w_hh,     // (2048, 512)
    float* __restrict__ hbuf,           // 2 x (64,512); hbuf[0] = h0 on entry
    unsigned short* __restrict__ hallb, // (3200, 512) bf16 h history
    int* __restrict__ cnt)              // >= 50 ints, zeroed
{
  __shared__ float s_w[8][512];    // [q*2 + dd_i][k], 16 KB
  __shared__ float s_g[2][4][64];  // [dd_i][gate][b], 2 KB
  const int tid = threadIdx.x;
  const int dd0 = blockIdx.x * 2;

  for (int idx = tid; idx < 1024; idx += 256) {
    int row = idx >> 7;          // 0..7: q = row>>1, dd_i = row&1
    int k4 = (idx & 127) << 2;
    int q_ = row >> 1, dd_i = row & 1;
    *(float4*)&s_w[row][k4] =
        *(const float4*)(w_hh + (size_t)(q_ * 512 + dd0 + dd_i) * 512 + k4);
  }
  const int b = tid & 63;
  const int q = tid >> 6;
  float c = 0.f;
  __syncthreads();

  for (int t = 0; t < 50; ++t) {
    const float* hc = hbuf + (t & 1) * 32768 + b * 512;
    const float* xr = xgT + (size_t)t * 131072 + (size_t)(q * 512 + dd0) * 64 + b;
    float a0 = xr[0], a1 = xr[64];
    const float* w0 = s_w[q * 2 + 0];
    const float* w1 = s_w[q * 2 + 1];
#pragma unroll 8
    for (int k = 0; k < 512; k += 4) {
      float4 h4 = *(const float4*)(hc + k);
      float4 u = *(const float4*)(w0 + k);
      float4 v = *(const float4*)(w1 + k);
      a0 = fmaf(h4.x, u.x, fmaf(h4.y, u.y, fmaf(h4.z, u.z, fmaf(h4.w, u.w, a0))));
      a1 = fmaf(h4.x, v.x, fmaf(h4.y, v.y, fmaf(h4.z, v.z, fmaf(h4.w, v.w, a1))));
    }
    s_g[0][q][b] = a0;
    s_g[1][q][b] = a1;
    __syncthreads();
    if (q < 2) {
      float gi = s_g[q][0][b], gf = s_g[q][1][b];
      float gg = s_g[q][2][b], go = s_g[q][3][b];
      float ig = 1.f / (1.f + expf(-gi));
      float fg = 1.f / (1.f + expf(-gf));
      float og = 1.f / (1.f + expf(-go));
      float gt = tanhf(gg);
      c = fmaf(fg, c, ig * gt);
      float h = og * tanhf(c);
      const int dd = dd0 + q;
      hbuf[((t + 1) & 1) * 32768 + b * 512 + dd] = h;
      hallb[((size_t)t * 64 + b) * 512 + dd] = f2b(h);
    }
    __syncthreads();  // drains vmcnt before barrier
    if (tid == 0) {
      __threadfence();            // release
      atomicAdd(&cnt[t], 1);
      while (__hip_atomic_load(&cnt[t], __ATOMIC_RELAXED,
                               __HIP_MEMORY_SCOPE_AGENT) < LSTM_BLOCKS) {
        __builtin_amdgcn_s_sleep(2);
      }
      __threadfence();            // acquire
    }
    __syncthreads();
  }
}

// ============================================================================
// Stage 4 (fallback): one LSTM step per launch (hang-proof, slower). Used only
// if the cooperative launch is rejected by the runtime/capture.
// ============================================================================
__global__ __launch_bounds__(256) void k_lstm_step1(
    const float* __restrict__ xgT, const float* __restrict__ w_hh,
    const float* __restrict__ hin, float* __restrict__ hout,
    unsigned short* __restrict__ hallb_t, float* __restrict__ cbuf, int t)
{
  __shared__ float s_w[8][512];
  __shared__ float s_g[2][4][64];
  const int tid = threadIdx.x;
  const int dd0 = blockIdx.x * 2;

  for (int idx = tid; idx < 1024; idx += 256) {
    int row = idx >> 7;
    int k4 = (idx & 127) << 2;
    int q_ = row >> 1, dd_i = row & 1;
    *(float4*)&s_w[row][k4] =
        *(const float4*)(w_hh + (size_t)(q_ * 512 + dd0 + dd_i) * 512 + k4);
  }
  const int b = tid & 63;
  const int q = tid >> 6;
  __syncthreads();

  const float* hc = hin + b * 512;
  const float* xr = xgT + (size_t)t * 131072 + (size_t)(q * 512 + dd0) * 64 + b;
  float a0 = xr[0], a1 = xr[64];
  const float* w0 = s_w[q * 2 + 0];
  const float* w1 = s_w[q * 2 + 1];
#pragma unroll 8
  for (int k = 0; k < 512; k += 4) {
    float4 h4 = *(const float4*)(hc + k);
    float4 u = *(const float4*)(w0 + k);
    float4 v = *(const float4*)(w1 + k);
    a0 = fmaf(h4.x, u.x, fmaf(h4.y, u.y, fmaf(h4.z, u.z, fmaf(h4.w, u.w, a0))));
    a1 = fmaf(h4.x, v.x, fmaf(h4.y, v.y, fmaf(h4.z, v.z, fmaf(h4.w, v.w, a1))));
  }
  s_g[0][q][b] = a0;
  s_g[1][q][b] = a1;
  __syncthreads();
  if (q < 2) {
    const int dd = dd0 + q;
    float gi = s_g[q][0][b], gf = s_g[q][1][b];
    float gg = s_g[q][2][b], go = s_g[q][3][b];
    float ig = 1.f / (1.f + expf(-gi));
    float fg = 1.f / (1.f + expf(-gf));
    float og = 1.f / (1.f + expf(-go));
    float gt = tanhf(gg);
    float c = fmaf(fg, cbuf[b * 512 + dd], ig * gt);
    float h = og * tanhf(c);
    cbuf[b * 512 + dd] = c;
    hout[b * 512 + dd] = h;
    hallb_t[(size_t)b * 512 + dd] = f2b(h);
  }
}

// ============================================================================
extern "C" void kernel_launch(void* const* d_in, const int* in_sizes, int n_in,
                              void* d_out, int out_size, void* d_ws,
                              size_t ws_size, hipStream_t stream) {
  const float* mask   = (const float*)d_in[0];
  const int*   tgt    = (const int*)d_in[1];
  const float* w1     = (const float*)d_in[2];
  const float* b1     = (const float*)d_in[3];
  const float* w2     = (const float*)d_in[4];
  const float* b2     = (const float*)d_in[5];
  const float* feat_w = (const float*)d_in[6];
  const float* feat_b = (const float*)d_in[7];
  const float* ctx_w  = (const float*)d_in[8];
  const float* ctx_b  = (const float*)d_in[9];
  const float* temb   = (const float*)d_in[10];
  const float* w_ih   = (const float*)d_in[11];
  const float* w_hh_p = (const float*)d_in[12];
  const float* b_ih   = (const float*)d_in[13];
  const float* b_hh   = (const float*)d_in[14];
  const float* head_w = (const float*)d_in[15];
  const float* head_b = (const float*)d_in[16];

  float* ws = (float*)d_ws;
  // float-unit offsets; total 9,109,568 floats = 36.4 MB
  float* part  = ws;                       // [0, 65536)
  float* hbuf  = ws + 65536;               // [65536, 131072)  2 x (64,512)
  float* ctx   = ws + 131072;              // [131072, 163840)
  int*   cnt   = (int*)(ws + 163840);      // [163840, 163904) 64 ints
  unsigned short* Ab16  = (unsigned short*)(ws + 163904);   // 819200 fl
  unsigned short* hallb = Ab16;            // overlay: Ab16 dead after gemm<0>
  unsigned short* wihb  = (unsigned short*)(ws + 983104);   // 524288 fl
  unsigned short* hwb   = (unsigned short*)(ws + 1507392);  // 1048576 fl
  float* xgT   = ws + 2555968;             // 6553600 fl, ends 9109568
  float* cbuf  = part;                     // overlay: part dead after pool_h0
  float* out   = (float*)d_out;            // (64,50,4096)

  k_conv<<<2048, 512, 0, stream>>>(mask, w1, b1, w2, b2, part);
  k_f2b<<<1024, 256, 0, stream>>>(w_ih, wihb, 1048576);
  k_f2b<<<2048, 256, 0, stream>>>(head_w, hwb, 2097152);
  k_zero<<<1, 64, 0, stream>>>(cnt);
  k_pool_h0<<<64, 256, 0, stream>>>(part, feat_w, feat_b, hbuf);
  k_ctx<<<64, 256, 0, stream>>>(hbuf, ctx_w, ctx_b, ctx);
  k_build_A<<<3200, 128, 0, stream>>>(temb, tgt, ctx, Ab16);
  k_gemm_mfma<0><<<25 * 16, 256, 0, stream>>>(Ab16, wihb, b_ih, b_hh, xgT, 16);

  // Persistent LSTM via cooperative launch (co-residency guaranteed -> the
  // grid barrier cannot deadlock). On any launch error, fall back to 50
  // per-step launches (hang-proof, proven structure).
  {
    const float* xgT_c = xgT;
    const float* whh_c = w_hh_p;
    float* hbuf_c = hbuf;
    unsigned short* hallb_c = hallb;
    int* cnt_c = cnt;
    void* args[] = {(void*)&xgT_c, (void*)&whh_c, (void*)&hbuf_c,
                    (void*)&hallb_c, (void*)&cnt_c};
    hipError_t e = hipLaunchCooperativeKernel(
        (const void*)k_lstm_all, dim3(LSTM_BLOCKS), dim3(256), args, 0, stream);
    if (e != hipSuccess) {
      (void)hipGetLastError();  // clear sticky error; stream state unaffected
      k_zero_f<<<128, 256, 0, stream>>>(cbuf);
      for (int t = 0; t < 50; t++) {
        const float* hin = hbuf + (t & 1) * 32768;
        float* hout = hbuf + ((t + 1) & 1) * 32768;
        k_lstm_step1<<<256, 256, 0, stream>>>(
            xgT, w_hh_p, hin, hout, hallb + (size_t)t * 32768, cbuf, t);
      }
    }
  }

  k_gemm_mfma<1><<<25 * 32, 256, 0, stream>>>(hallb, hwb, head_b, nullptr, out, 32);
}

// Round 6
// 1963.821 us; speedup vs baseline: 1.1721x; 1.1721x over previous
//
#include <hip/hip_runtime.h>
#include <cmath>

typedef __attribute__((ext_vector_type(8))) short bf16x8;
typedef __attribute__((ext_vector_type(4))) float f32x4;

#define LSTM_NB 32

__device__ __forceinline__ unsigned short f2b(float x) {
  unsigned u = __builtin_bit_cast(unsigned, x);
  u += 0x7fffu + ((u >> 16) & 1u);
  return (unsigned short)(u >> 16);
}

__device__ __forceinline__ void gload16(const void* g, void* l) {
  __builtin_amdgcn_global_load_lds(
      (const __attribute__((address_space(1))) void*)g,
      (__attribute__((address_space(3))) void*)l, 16, 0, 0);
}

// Agent-scope coherent 16B load (2 x u64 relaxed atomics -> bypass L1/L2).
__device__ __forceinline__ bf16x8 cload8(const unsigned short* p) {
  union { unsigned long long q[2]; bf16x8 v; } u;
  u.q[0] = __hip_atomic_load((const unsigned long long*)(const void*)p,
                             __ATOMIC_RELAXED, __HIP_MEMORY_SCOPE_AGENT);
  u.q[1] = __hip_atomic_load((const unsigned long long*)(const void*)(p + 4),
                             __ATOMIC_RELAXED, __HIP_MEMORY_SCOPE_AGENT);
  return u.v;
}

// ============================================================================
// Stage 1: fused conv1 + relu + maxpool2x2 + conv2 + relu + spatial-sum.
// Tile = 32x16 pooled px: LDS ~61 KB -> 2 blocks/CU. Grid 2048.
// ============================================================================
__global__ __launch_bounds__(512) void k_conv(
    const float* __restrict__ mask, const float* __restrict__ w1,
    const float* __restrict__ b1, const float* __restrict__ w2,
    const float* __restrict__ b2, float* __restrict__ part)
{
  __shared__ float s_p1[16][18 * 36];
  __shared__ float s_w1[144];
  __shared__ float s_b1[16];
  __shared__ float s_w2[4608];
  __shared__ float s_b2[32];

  const int tid = threadIdx.x;
  const int b = blockIdx.x >> 5;
  const int tile = blockIdx.x & 31;
  const int px0 = (tile & 3) * 32, py0 = (tile >> 2) * 16;
  const float* mb = mask + (size_t)b * 65536;

  for (int i = tid; i < 144; i += 512) s_w1[i] = w1[i];
  for (int i = tid; i < 4608; i += 512) s_w2[i] = w2[i];
  if (tid < 16) s_b1[tid] = b1[tid];
  if (tid < 32) s_b2[tid] = b2[tid];
  __syncthreads();

  for (int idx = tid; idx < 18 * 34; idx += 512) {
    int ly = idx / 34, lx = idx - ly * 34;
    int py = py0 - 1 + ly, px = px0 - 1 + lx;
    if (py < 0 || py >= 128 || px < 0 || px >= 128) {
      for (int o = 0; o < 16; o++) s_p1[o][ly * 36 + lx] = 0.f;
    } else {
      float patch[4][4];
      int gy0 = 2 * py - 1, gx0 = 2 * px - 1;
#pragma unroll
      for (int i = 0; i < 4; i++) {
        int gy = gy0 + i;
        bool yok = (gy >= 0 && gy < 256);
#pragma unroll
        for (int j = 0; j < 4; j++) {
          int gx = gx0 + j;
          patch[i][j] = (yok && gx >= 0 && gx < 256) ? mb[gy * 256 + gx] : 0.f;
        }
      }
      for (int o = 0; o < 16; o++) {
        float m = 0.f;
#pragma unroll
        for (int dy = 0; dy < 2; dy++)
#pragma unroll
          for (int dx = 0; dx < 2; dx++) {
            float v = s_b1[o];
#pragma unroll
            for (int ky = 0; ky < 3; ky++)
#pragma unroll
              for (int kx = 0; kx < 3; kx++)
                v = fmaf(patch[dy + ky][dx + kx], s_w1[o * 9 + ky * 3 + kx], v);
            m = fmaxf(m, v);
          }
        s_p1[o][ly * 36 + lx] = m;
      }
    }
  }
  __syncthreads();

  const int ocg = tid >> 6;
  const int sp = tid & 63;
  const int sx = (sp & 7) * 4, sy = (sp >> 3) * 2;
  float acc[4][8];
#pragma unroll
  for (int a = 0; a < 4; a++)
#pragma unroll
    for (int q = 0; q < 8; q++) acc[a][q] = 0.f;

  for (int ic = 0; ic < 16; ic++) {
    float p[4][6];
#pragma unroll
    for (int i = 0; i < 4; i++) {
      const float* row = &s_p1[ic][(sy + i) * 36 + sx];
#pragma unroll
      for (int j = 0; j < 6; j++) p[i][j] = row[j];
    }
#pragma unroll
    for (int o4 = 0; o4 < 4; o4++) {
      const int oc = ocg * 4 + o4;
      const float* w = &s_w2[(oc * 16 + ic) * 9];
      float w00 = w[0], w01 = w[1], w02 = w[2];
      float w10 = w[3], w11 = w[4], w12 = w[5];
      float w20 = w[6], w21 = w[7], w22 = w[8];
#pragma unroll
      for (int y = 0; y < 2; y++)
#pragma unroll
        for (int x = 0; x < 4; x++) {
          float s = acc[o4][y * 4 + x];
          s = fmaf(p[y][x], w00, s);
          s = fmaf(p[y][x + 1], w01, s);
          s = fmaf(p[y][x + 2], w02, s);
          s = fmaf(p[y + 1][x], w10, s);
          s = fmaf(p[y + 1][x + 1], w11, s);
          s = fmaf(p[y + 1][x + 2], w12, s);
          s = fmaf(p[y + 2][x], w20, s);
          s = fmaf(p[y + 2][x + 1], w21, s);
          s = fmaf(p[y + 2][x + 2], w22, s);
          acc[o4][y * 4 + x] = s;
        }
    }
  }

  const int lane = tid & 63;
#pragma unroll
  for (int o4 = 0; o4 < 4; o4++) {
    float bv = s_b2[ocg * 4 + o4];
    float s = 0.f;
#pragma unroll
    for (int q = 0; q < 8; q++) s += fmaxf(acc[o4][q] + bv, 0.f);
    for (int off = 32; off > 0; off >>= 1) s += __shfl_down(s, off, 64);
    if (lane == 0) part[(b * 32 + tile) * 32 + ocg * 4 + o4] = s;
  }
}

// ============================================================================
// Stage 2a: tile partials -> pooled mean -> h0 GEMM (K=32).
// Writes fp32 h0 (ctx + fallback) AND bf16 hi/lo h0 (persistent-MFMA LSTM).
// ============================================================================
__global__ __launch_bounds__(256) void k_pool_h0(
    const float* __restrict__ part, const float* __restrict__ feat_w,
    const float* __restrict__ feat_b, float* __restrict__ h0,
    unsigned short* __restrict__ h0b, unsigned short* __restrict__ h0lo)
{
  const int b = blockIdx.x, tid = threadIdx.x;
  __shared__ float pl[32];
  if (tid < 32) {
    float s = 0.f;
    for (int t = 0; t < 32; t++) s += part[(b * 32 + t) * 32 + tid];
    pl[tid] = s * (1.0f / 16384.0f);
  }
  __syncthreads();
  for (int j = tid; j < 512; j += 256) {
    float acc = feat_b[j];
    const float* w = feat_w + j * 32;
#pragma unroll
    for (int ic = 0; ic < 32; ic++) acc = fmaf(pl[ic], w[ic], acc);
    h0[b * 512 + j] = acc;
    unsigned short hh = f2b(acc);
    h0b[b * 512 + j] = hh;
    h0lo[b * 512 + j] = f2b(acc - __builtin_bit_cast(float, (unsigned)hh << 16));
  }
}

// ============================================================================
// Stage 2b: ctx = h0 @ ctx_w.T + ctx_b.
// ============================================================================
__global__ __launch_bounds__(256) void k_ctx(
    const float* __restrict__ h0, const float* __restrict__ ctx_w,
    const float* __restrict__ ctx_b, float* __restrict__ ctx)
{
  const int b = blockIdx.x, tid = threadIdx.x;
  __shared__ float hs[512];
  for (int k = tid; k < 512; k += 256) hs[k] = h0[b * 512 + k];
  __syncthreads();
  for (int j = tid; j < 512; j += 256) {
    const float* w = ctx_w + (size_t)j * 512;
    float s0 = 0.f, s1 = 0.f, s2 = 0.f, s3 = 0.f;
    for (int k = 0; k < 512; k += 4) {
      float4 w4 = *(const float4*)(w + k);
      s0 = fmaf(hs[k], w4.x, s0);
      s1 = fmaf(hs[k + 1], w4.y, s1);
      s2 = fmaf(hs[k + 2], w4.z, s2);
      s3 = fmaf(hs[k + 3], w4.w, s3);
    }
    ctx[b * 512 + j] = ctx_b[j] + ((s0 + s1) + (s2 + s3));
  }
}

// ============================================================================
// fp32 -> bf16 (RNE), 4 elems/thread.
// ============================================================================
__global__ __launch_bounds__(256) void k_f2b(
    const float* __restrict__ in, unsigned short* __restrict__ out, int n)
{
  int i = (blockIdx.x * 256 + threadIdx.x) * 4;
  if (i < n) {
    float4 v = *(const float4*)(in + i);
    unsigned lo = (unsigned)f2b(v.x) | ((unsigned)f2b(v.y) << 16);
    unsigned hi = (unsigned)f2b(v.z) | ((unsigned)f2b(v.w) << 16);
    *(uint2*)(out + i) = make_uint2(lo, hi);
  }
}

// ============================================================================
// Zero helpers (ws poisoned to 0xAA before timing; re-init every call).
// ============================================================================
__global__ __launch_bounds__(64) void k_zero(int* __restrict__ p) {
  p[threadIdx.x] = 0;
}
__global__ __launch_bounds__(256) void k_zero_f(float* __restrict__ p) {
  p[blockIdx.x * 256 + threadIdx.x] = 0.f;
}

// ============================================================================
// Stage 3a: A[(t*64+b)][k] = bf16(tok_emb[tok][k] + ctx[b][k])
// ============================================================================
__global__ __launch_bounds__(128) void k_build_A(
    const float* __restrict__ tok_emb, const int* __restrict__ tgt,
    const float* __restrict__ ctx, unsigned short* __restrict__ A)
{
  const int r = blockIdx.x;
  const int t = r >> 6, b = r & 63;
  const int tok = (t == 0) ? 4096 : tgt[b * 50 + (t - 1)];
  const int i = threadIdx.x * 4;
  float4 ev = *(const float4*)(tok_emb + (size_t)tok * 512 + i);
  float4 cv = *(const float4*)(ctx + b * 512 + i);
  unsigned lo = (unsigned)f2b(ev.x + cv.x) | ((unsigned)f2b(ev.y + cv.y) << 16);
  unsigned hi = (unsigned)f2b(ev.z + cv.z) | ((unsigned)f2b(ev.w + cv.w) << 16);
  *(uint2*)(A + (size_t)r * 512 + i) = make_uint2(lo, hi);
}

// ============================================================================
// bf16 MFMA GEMM (m97 structure): C(MxN) = A(Mx512) @ B(Nx512)^T + bias.
// MODE 0: xgates; C TRANSPOSED (t, gate-dd, b) = (50,2048,64).
// MODE 1: head; C remapped (t*64+b, v) -> (b*50+t, v).
// ============================================================================
template <int MODE>
__global__ __launch_bounds__(256) void k_gemm_mfma(
    const unsigned short* __restrict__ A, const unsigned short* __restrict__ B,
    const float* __restrict__ bias_a, const float* __restrict__ bias_b,
    float* __restrict__ C, int NB)
{
  __shared__ unsigned short sA[128 * 32];
  __shared__ unsigned short sB[128 * 32];
  const int tid = threadIdx.x;
  const int bx = blockIdx.x % NB, by = blockIdx.x / NB;
  const int lane = tid & 63, wv = tid >> 6;
  const int wr = wv >> 1, wc = wv & 1;
  const unsigned short* Ab = A + (size_t)by * 128 * 512;
  const unsigned short* Bb = B + (size_t)bx * 128 * 512;

  f32x4 acc[4][4];
#pragma unroll
  for (int m = 0; m < 4; m++)
#pragma unroll
    for (int n = 0; n < 4; n++) acc[m][n] = (f32x4){0.f, 0.f, 0.f, 0.f};

  const int r0 = tid >> 2, c0 = (tid & 3) * 8;
  const int idx1 = tid + 256;
  const int r1 = idx1 >> 2, c1 = (idx1 & 3) * 8;
  unsigned short* lA0 = sA + (size_t)wv * 512;
  unsigned short* lA1 = sA + 2048 + (size_t)wv * 512;
  unsigned short* lB0 = sB + (size_t)wv * 512;
  unsigned short* lB1 = sB + 2048 + (size_t)wv * 512;

  const int frow = lane & 15;
  const int foff = (lane >> 4) * 8;

  for (int kc = 0; kc < 512; kc += 32) {
    gload16(Ab + (size_t)r0 * 512 + kc + c0, lA0);
    gload16(Ab + (size_t)r1 * 512 + kc + c1, lA1);
    gload16(Bb + (size_t)r0 * 512 + kc + c0, lB0);
    gload16(Bb + (size_t)r1 * 512 + kc + c1, lB1);
    __syncthreads();

    bf16x8 af[4], bfr[4];
#pragma unroll
    for (int m = 0; m < 4; m++)
      af[m] = *(const bf16x8*)(sA + (wr * 64 + m * 16 + frow) * 32 + foff);
#pragma unroll
    for (int n = 0; n < 4; n++)
      bfr[n] = *(const bf16x8*)(sB + (wc * 64 + n * 16 + frow) * 32 + foff);
#pragma unroll
    for (int m = 0; m < 4; m++)
#pragma unroll
      for (int n = 0; n < 4; n++)
        acc[m][n] = __builtin_amdgcn_mfma_f32_16x16x32_bf16(
            af[m], bfr[n], acc[m][n], 0, 0, 0);
    __syncthreads();
  }

  // C/D layout (m91-verified): col = lane&15, row = (lane>>4)*4 + j
#pragma unroll
  for (int n = 0; n < 4; n++) {
    const int gc = bx * 128 + wc * 64 + n * 16 + (lane & 15);
    const float bv = (MODE == 0) ? (bias_a[gc] + bias_b[gc]) : bias_a[gc];
#pragma unroll
    for (int m = 0; m < 4; m++) {
      const int rb = by * 128 + wr * 64 + m * 16 + (lane >> 4) * 4;
#pragma unroll
      for (int j = 0; j < 4; j++) {
        const int r = rb + j;
        float v = acc[m][n][j] + bv;
        int t = r >> 6, bb = r & 63;
        if (MODE == 0) {
          C[(size_t)t * 131072 + (size_t)gc * 64 + bb] = v;
        } else {
          C[((size_t)bb * 50 + t) * 4096 + gc] = v;
        }
      }
    }
  }
}

// ============================================================================
// Stage 4 (primary): PERSISTENT MFMA LSTM, one cooperative dispatch, 32 blocks.
// Wave = one gate x 16 hidden dims x 64 batches; w_hh fragments (hi/lo bf16
// split for fp32-equivalent accuracy) live in 128 VGPRs for all 50 steps.
// NO cache fences: h state moves via agent-scope relaxed atomics (bypass the
// non-coherent L1/L2); __syncthreads drains vmcnt(0) before the tid-0 arrival
// atomic, which is the release ordering. Round-5's __threadfence (L2
// writeback+invalidate per step) was the 40 us/step cost — eliminated.
// ============================================================================
__global__ __launch_bounds__(256, 1) void k_lstm_mfma(
    const float* __restrict__ xgT,            // (50,2048,64) xgates (biased)
    const float* __restrict__ w_hh,           // (2048,512) fp32
    const unsigned short* __restrict__ h0b,   // (64,512) bf16 hi
    const unsigned short* __restrict__ h0lo,  // (64,512) bf16 lo
    unsigned short* __restrict__ hallb,       // (50,64,512) bf16 hi history
    unsigned short* __restrict__ hlo,         // (2,64,512) bf16 lo ping-pong
    int* __restrict__ cnt)                    // >= 50 ints, zeroed
{
  __shared__ float s_g[4][64][17];  // [gate][batch][dd_rel], +1 pad
  const int tid = threadIdx.x;
  const int kb = blockIdx.x;        // dims [16*kb, 16*kb+16)
  const int g = tid >> 6;           // gate = wave
  const int lane = tid & 63;
  const int frow = lane & 15;
  const int foff = (lane >> 4) * 8;

  // Load weight fragments once: w = w_hi + w_lo (bf16 split).
  bf16x8 whi[16], wlo[16];
  {
    const float* wrow = w_hh + (size_t)(g * 512 + kb * 16 + frow) * 512;
#pragma unroll
    for (int kf = 0; kf < 16; kf++) {
      float tmp[8];
      *(float4*)tmp = *(const float4*)(wrow + kf * 32 + foff);
      *(float4*)(tmp + 4) = *(const float4*)(wrow + kf * 32 + foff + 4);
#pragma unroll
      for (int j = 0; j < 8; j++) {
        unsigned short h = f2b(tmp[j]);
        whi[kf][j] = (short)h;
        wlo[kf][j] =
            (short)f2b(tmp[j] - __builtin_bit_cast(float, (unsigned)h << 16));
      }
    }
  }

  float c[4] = {0.f, 0.f, 0.f, 0.f};  // cell state: (dd = kb*16+g*4+i, b=lane)
  const int b2 = tid & 63, dd2 = tid >> 6;

  for (int t = 0; t < 50; ++t) {
    const unsigned short* Hhi = t ? hallb + (size_t)(t - 1) * 32768 : h0b;
    const unsigned short* Hlo = t ? hlo + (size_t)((t - 1) & 1) * 32768 : h0lo;

    f32x4 acc[4];
#pragma unroll
    for (int mt = 0; mt < 4; mt++) acc[mt] = (f32x4){0.f, 0.f, 0.f, 0.f};
#pragma unroll
    for (int kf = 0; kf < 16; kf++) {
#pragma unroll
      for (int mt = 0; mt < 4; mt++) {
        const int off = (mt * 16 + frow) * 512 + kf * 32 + foff;
        bf16x8 ah = cload8(Hhi + off);
        bf16x8 al = cload8(Hlo + off);
        acc[mt] = __builtin_amdgcn_mfma_f32_16x16x32_bf16(ah, whi[kf], acc[mt], 0, 0, 0);
        acc[mt] = __builtin_amdgcn_mfma_f32_16x16x32_bf16(ah, wlo[kf], acc[mt], 0, 0, 0);
        acc[mt] = __builtin_amdgcn_mfma_f32_16x16x32_bf16(al, whi[kf], acc[mt], 0, 0, 0);
      }
    }
    // C/D: col = lane&15 (dd_rel), row = (lane>>4)*4 + j (batch)
#pragma unroll
    for (int mt = 0; mt < 4; mt++)
#pragma unroll
      for (int j = 0; j < 4; j++)
        s_g[g][mt * 16 + (lane >> 4) * 4 + j][frow] = acc[mt][j];
    __syncthreads();

    // c/h update: thread owns 4 cells (dd = kb*16 + dd2*4 + i, batch b2).
    const float* xr =
        xgT + (size_t)t * 131072 + (size_t)(kb * 16 + dd2 * 4) * 64 + b2;
    unsigned long long qh = 0, ql = 0;
#pragma unroll
    for (int i = 0; i < 4; i++) {
      float gi = s_g[0][b2][dd2 * 4 + i] + xr[(size_t)(0 * 512 + i) * 64];
      float gf = s_g[1][b2][dd2 * 4 + i] + xr[(size_t)(1 * 512 + i) * 64];
      float gg = s_g[2][b2][dd2 * 4 + i] + xr[(size_t)(2 * 512 + i) * 64];
      float go = s_g[3][b2][dd2 * 4 + i] + xr[(size_t)(3 * 512 + i) * 64];
      float ig = 1.f / (1.f + expf(-gi));
      float fg = 1.f / (1.f + expf(-gf));
      float og = 1.f / (1.f + expf(-go));
      float gt = tanhf(gg);
      c[i] = fmaf(fg, c[i], ig * gt);
      float h = og * tanhf(c[i]);
      unsigned short hh = f2b(h);
      unsigned short hl =
          f2b(h - __builtin_bit_cast(float, (unsigned)hh << 16));
      qh |= (unsigned long long)hh << (16 * i);
      ql |= (unsigned long long)hl << (16 * i);
    }
    const size_t ho = (size_t)b2 * 512 + kb * 16 + dd2 * 4;
    __hip_atomic_store((unsigned long long*)(hallb + (size_t)t * 32768 + ho),
                       qh, __ATOMIC_RELAXED, __HIP_MEMORY_SCOPE_AGENT);
    __hip_atomic_store(
        (unsigned long long*)(hlo + (size_t)(t & 1) * 32768 + ho), ql,
        __ATOMIC_RELAXED, __HIP_MEMORY_SCOPE_AGENT);
    __syncthreads();  // drains vmcnt(0) on every wave -> stores visible
    if (tid == 0) {
      __hip_atomic_fetch_add(&cnt[t], 1, __ATOMIC_RELAXED,
                             __HIP_MEMORY_SCOPE_AGENT);
      while (__hip_atomic_load(&cnt[t], __ATOMIC_RELAXED,
                               __HIP_MEMORY_SCOPE_AGENT) < LSTM_NB) {
        __builtin_amdgcn_s_sleep(1);
      }
    }
    __syncthreads();
  }
}

// ============================================================================
// Stage 4 (fallback): one LSTM step per launch (hang-proof). Used only if the
// cooperative launch is rejected.
// ============================================================================
__global__ __launch_bounds__(256) void k_lstm_step1(
    const float* __restrict__ xgT, const float* __restrict__ w_hh,
    const float* __restrict__ hin, float* __restrict__ hout,
    unsigned short* __restrict__ hallb_t, float* __restrict__ cbuf, int t)
{
  __shared__ float s_w[8][512];
  __shared__ float s_g[2][4][64];
  const int tid = threadIdx.x;
  const int dd0 = blockIdx.x * 2;

  for (int idx = tid; idx < 1024; idx += 256) {
    int row = idx >> 7;
    int k4 = (idx & 127) << 2;
    int q_ = row >> 1, dd_i = row & 1;
    *(float4*)&s_w[row][k4] =
        *(const float4*)(w_hh + (size_t)(q_ * 512 + dd0 + dd_i) * 512 + k4);
  }
  const int b = tid & 63;
  const int q = tid >> 6;
  __syncthreads();

  const float* hc = hin + b * 512;
  const float* xr = xgT + (size_t)t * 131072 + (size_t)(q * 512 + dd0) * 64 + b;
  float a0 = xr[0], a1 = xr[64];
  const float* w0 = s_w[q * 2 + 0];
  const float* w1 = s_w[q * 2 + 1];
#pragma unroll 8
  for (int k = 0; k < 512; k += 4) {
    float4 h4 = *(const float4*)(hc + k);
    float4 u = *(const float4*)(w0 + k);
    float4 v = *(const float4*)(w1 + k);
    a0 = fmaf(h4.x, u.x, fmaf(h4.y, u.y, fmaf(h4.z, u.z, fmaf(h4.w, u.w, a0))));
    a1 = fmaf(h4.x, v.x, fmaf(h4.y, v.y, fmaf(h4.z, v.z, fmaf(h4.w, v.w, a1))));
  }
  s_g[0][q][b] = a0;
  s_g[1][q][b] = a1;
  __syncthreads();
  if (q < 2) {
    const int dd = dd0 + q;
    float gi = s_g[q][0][b], gf = s_g[q][1][b];
    float gg = s_g[q][2][b], go = s_g[q][3][b];
    float ig = 1.f / (1.f + expf(-gi));
    float fg = 1.f / (1.f + expf(-gf));
    float og = 1.f / (1.f + expf(-go));
    float gt = tanhf(gg);
    float c = fmaf(fg, cbuf[b * 512 + dd], ig * gt);
    float h = og * tanhf(c);
    cbuf[b * 512 + dd] = c;
    hout[b * 512 + dd] = h;
    hallb_t[(size_t)b * 512 + dd] = f2b(h);
  }
}

// ============================================================================
extern "C" void kernel_launch(void* const* d_in, const int* in_sizes, int n_in,
                              void* d_out, int out_size, void* d_ws,
                              size_t ws_size, hipStream_t stream) {
  const float* mask   = (const float*)d_in[0];
  const int*   tgt    = (const int*)d_in[1];
  const float* w1     = (const float*)d_in[2];
  const float* b1     = (const float*)d_in[3];
  const float* w2     = (const float*)d_in[4];
  const float* b2     = (const float*)d_in[5];
  const float* feat_w = (const float*)d_in[6];
  const float* feat_b = (const float*)d_in[7];
  const float* ctx_w  = (const float*)d_in[8];
  const float* ctx_b  = (const float*)d_in[9];
  const float* temb   = (const float*)d_in[10];
  const float* w_ih   = (const float*)d_in[11];
  const float* w_hh_p = (const float*)d_in[12];
  const float* b_ih   = (const float*)d_in[13];
  const float* b_hh   = (const float*)d_in[14];
  const float* head_w = (const float*)d_in[15];
  const float* head_b = (const float*)d_in[16];

  float* ws = (float*)d_ws;
  // float-unit offsets; total 9,175,104 floats = 36.7 MB (< proven 39.85 MB)
  float* part  = ws;                       // [0, 65536)
  float* hbuf  = ws + 65536;               // [65536, 131072)  fp32 ping-pong
  float* ctx   = ws + 131072;              // [131072, 163840)
  int*   cnt   = (int*)(ws + 163840);      // [163840, 163904) 64 ints
  unsigned short* h0b  = (unsigned short*)(ws + 163904);    // 16384 fl
  unsigned short* h0lo = (unsigned short*)(ws + 180288);    // 16384 fl
  unsigned short* hlo  = (unsigned short*)(ws + 196672);    // 32768 fl
  unsigned short* Ab16 = (unsigned short*)(ws + 229440);    // 819200 fl
  unsigned short* hallb = Ab16;            // overlay: Ab16 dead after gemm<0>
  unsigned short* wihb = (unsigned short*)(ws + 1048640);   // 524288 fl
  unsigned short* hwb  = (unsigned short*)(ws + 1572928);   // 1048576 fl
  float* xgT   = ws + 2621504;             // 6553600 fl, ends 9175104
  float* cbuf  = part;                     // overlay: part dead after pool_h0
  float* out   = (float*)d_out;            // (64,50,4096)

  k_conv<<<2048, 512, 0, stream>>>(mask, w1, b1, w2, b2, part);
  k_f2b<<<1024, 256, 0, stream>>>(w_ih, wihb, 1048576);
  k_f2b<<<2048, 256, 0, stream>>>(head_w, hwb, 2097152);
  k_zero<<<1, 64, 0, stream>>>(cnt);
  k_pool_h0<<<64, 256, 0, stream>>>(part, feat_w, feat_b, hbuf, h0b, h0lo);
  k_ctx<<<64, 256, 0, stream>>>(hbuf, ctx_w, ctx_b, ctx);
  k_build_A<<<3200, 128, 0, stream>>>(temb, tgt, ctx, Ab16);
  k_gemm_mfma<0><<<25 * 16, 256, 0, stream>>>(Ab16, wihb, b_ih, b_hh, xgT, 16);

  // Persistent MFMA LSTM (cooperative -> co-residency guaranteed, hang-proof).
  {
    const float* xgT_c = xgT;
    const float* whh_c = w_hh_p;
    const unsigned short* h0b_c = h0b;
    const unsigned short* h0lo_c = h0lo;
    unsigned short* hallb_c = hallb;
    unsigned short* hlo_c = hlo;
    int* cnt_c = cnt;
    void* args[] = {(void*)&xgT_c,   (void*)&whh_c, (void*)&h0b_c,
                    (void*)&h0lo_c,  (void*)&hallb_c, (void*)&hlo_c,
                    (void*)&cnt_c};
    hipError_t e = hipLaunchCooperativeKernel(
        (const void*)k_lstm_mfma, dim3(LSTM_NB), dim3(256), args, 0, stream);
    if (e != hipSuccess) {
      (void)hipGetLastError();  // clear sticky error
      k_zero_f<<<128, 256, 0, stream>>>(cbuf);
      for (int t = 0; t < 50; t++) {
        const float* hin = hbuf + (t & 1) * 32768;
        float* hout = hbuf + ((t + 1) & 1) * 32768;
        k_lstm_step1<<<256, 256, 0, stream>>>(
            xgT, w_hh_p, hin, hout, hallb + (size_t)t * 32768, cbuf, t);
      }
    }
  }

  k_gemm_mfma<1><<<25 * 32, 256, 0, stream>>>(hallb, hwb, head_b, nullptr, out, 32);
}

// Round 7
// 782.180 us; speedup vs baseline: 2.9428x; 2.5107x over previous
//
#include <hip/hip_runtime.h>
#include <cmath>

typedef __attribute__((ext_vector_type(8))) short bf16x8;
typedef __attribute__((ext_vector_type(4))) float f32x4;
typedef __attribute__((ext_vector_type(4))) unsigned u32x4;

#define LSTM_NB 32

__device__ __forceinline__ unsigned short f2b(float x) {
  unsigned u = __builtin_bit_cast(unsigned, x);
  u += 0x7fffu + ((u >> 16) & 1u);
  return (unsigned short)(u >> 16);
}

__device__ __forceinline__ void gload16(const void* g, void* l) {
  __builtin_amdgcn_global_load_lds(
      (const __attribute__((address_space(1))) void*)g,
      (__attribute__((address_space(3))) void*)l, 16, 0, 0);
}

// Coherent (L1/L2-bypassing) coalesced 16B load: same coherence point the
// round-6 agent atomics used, but with normal vector-load coalescing.
__device__ __forceinline__ void cload16(const void* p, u32x4* dst) {
  asm volatile("global_load_dwordx4 %0, %1, off sc0 sc1"
               : "=v"(*dst)
               : "v"(p));
}

// ============================================================================
// Stage 1: fused conv1 + relu + maxpool2x2 + conv2 + relu + spatial-sum.
// Tile = 32x16 pooled px: LDS ~61 KB -> 2 blocks/CU. Grid 2048.
// ============================================================================
__global__ __launch_bounds__(512) void k_conv(
    const float* __restrict__ mask, const float* __restrict__ w1,
    const float* __restrict__ b1, const float* __restrict__ w2,
    const float* __restrict__ b2, float* __restrict__ part)
{
  __shared__ float s_p1[16][18 * 36];
  __shared__ float s_w1[144];
  __shared__ float s_b1[16];
  __shared__ float s_w2[4608];
  __shared__ float s_b2[32];

  const int tid = threadIdx.x;
  const int b = blockIdx.x >> 5;
  const int tile = blockIdx.x & 31;
  const int px0 = (tile & 3) * 32, py0 = (tile >> 2) * 16;
  const float* mb = mask + (size_t)b * 65536;

  for (int i = tid; i < 144; i += 512) s_w1[i] = w1[i];
  for (int i = tid; i < 4608; i += 512) s_w2[i] = w2[i];
  if (tid < 16) s_b1[tid] = b1[tid];
  if (tid < 32) s_b2[tid] = b2[tid];
  __syncthreads();

  for (int idx = tid; idx < 18 * 34; idx += 512) {
    int ly = idx / 34, lx = idx - ly * 34;
    int py = py0 - 1 + ly, px = px0 - 1 + lx;
    if (py < 0 || py >= 128 || px < 0 || px >= 128) {
      for (int o = 0; o < 16; o++) s_p1[o][ly * 36 + lx] = 0.f;
    } else {
      float patch[4][4];
      int gy0 = 2 * py - 1, gx0 = 2 * px - 1;
#pragma unroll
      for (int i = 0; i < 4; i++) {
        int gy = gy0 + i;
        bool yok = (gy >= 0 && gy < 256);
#pragma unroll
        for (int j = 0; j < 4; j++) {
          int gx = gx0 + j;
          patch[i][j] = (yok && gx >= 0 && gx < 256) ? mb[gy * 256 + gx] : 0.f;
        }
      }
      for (int o = 0; o < 16; o++) {
        float m = 0.f;
#pragma unroll
        for (int dy = 0; dy < 2; dy++)
#pragma unroll
          for (int dx = 0; dx < 2; dx++) {
            float v = s_b1[o];
#pragma unroll
            for (int ky = 0; ky < 3; ky++)
#pragma unroll
              for (int kx = 0; kx < 3; kx++)
                v = fmaf(patch[dy + ky][dx + kx], s_w1[o * 9 + ky * 3 + kx], v);
            m = fmaxf(m, v);
          }
        s_p1[o][ly * 36 + lx] = m;
      }
    }
  }
  __syncthreads();

  const int ocg = tid >> 6;
  const int sp = tid & 63;
  const int sx = (sp & 7) * 4, sy = (sp >> 3) * 2;
  float acc[4][8];
#pragma unroll
  for (int a = 0; a < 4; a++)
#pragma unroll
    for (int q = 0; q < 8; q++) acc[a][q] = 0.f;

  for (int ic = 0; ic < 16; ic++) {
    float p[4][6];
#pragma unroll
    for (int i = 0; i < 4; i++) {
      const float* row = &s_p1[ic][(sy + i) * 36 + sx];
#pragma unroll
      for (int j = 0; j < 6; j++) p[i][j] = row[j];
    }
#pragma unroll
    for (int o4 = 0; o4 < 4; o4++) {
      const int oc = ocg * 4 + o4;
      const float* w = &s_w2[(oc * 16 + ic) * 9];
      float w00 = w[0], w01 = w[1], w02 = w[2];
      float w10 = w[3], w11 = w[4], w12 = w[5];
      float w20 = w[6], w21 = w[7], w22 = w[8];
#pragma unroll
      for (int y = 0; y < 2; y++)
#pragma unroll
        for (int x = 0; x < 4; x++) {
          float s = acc[o4][y * 4 + x];
          s = fmaf(p[y][x], w00, s);
          s = fmaf(p[y][x + 1], w01, s);
          s = fmaf(p[y][x + 2], w02, s);
          s = fmaf(p[y + 1][x], w10, s);
          s = fmaf(p[y + 1][x + 1], w11, s);
          s = fmaf(p[y + 1][x + 2], w12, s);
          s = fmaf(p[y + 2][x], w20, s);
          s = fmaf(p[y + 2][x + 1], w21, s);
          s = fmaf(p[y + 2][x + 2], w22, s);
          acc[o4][y * 4 + x] = s;
        }
    }
  }

  const int lane = tid & 63;
#pragma unroll
  for (int o4 = 0; o4 < 4; o4++) {
    float bv = s_b2[ocg * 4 + o4];
    float s = 0.f;
#pragma unroll
    for (int q = 0; q < 8; q++) s += fmaxf(acc[o4][q] + bv, 0.f);
    for (int off = 32; off > 0; off >>= 1) s += __shfl_down(s, off, 64);
    if (lane == 0) part[(b * 32 + tile) * 32 + ocg * 4 + o4] = s;
  }
}

// ============================================================================
// Stage 2a: tile partials -> pooled mean -> h0 GEMM (K=32).
// Writes fp32 h0 (ctx + fallback) AND bf16 hi/lo h0 (persistent-MFMA LSTM).
// ============================================================================
__global__ __launch_bounds__(256) void k_pool_h0(
    const float* __restrict__ part, const float* __restrict__ feat_w,
    const float* __restrict__ feat_b, float* __restrict__ h0,
    unsigned short* __restrict__ h0b, unsigned short* __restrict__ h0lo)
{
  const int b = blockIdx.x, tid = threadIdx.x;
  __shared__ float pl[32];
  if (tid < 32) {
    float s = 0.f;
    for (int t = 0; t < 32; t++) s += part[(b * 32 + t) * 32 + tid];
    pl[tid] = s * (1.0f / 16384.0f);
  }
  __syncthreads();
  for (int j = tid; j < 512; j += 256) {
    float acc = feat_b[j];
    const float* w = feat_w + j * 32;
#pragma unroll
    for (int ic = 0; ic < 32; ic++) acc = fmaf(pl[ic], w[ic], acc);
    h0[b * 512 + j] = acc;
    unsigned short hh = f2b(acc);
    h0b[b * 512 + j] = hh;
    h0lo[b * 512 + j] = f2b(acc - __builtin_bit_cast(float, (unsigned)hh << 16));
  }
}

// ============================================================================
// Stage 2b: ctx = h0 @ ctx_w.T + ctx_b.
// ============================================================================
__global__ __launch_bounds__(256) void k_ctx(
    const float* __restrict__ h0, const float* __restrict__ ctx_w,
    const float* __restrict__ ctx_b, float* __restrict__ ctx)
{
  const int b = blockIdx.x, tid = threadIdx.x;
  __shared__ float hs[512];
  for (int k = tid; k < 512; k += 256) hs[k] = h0[b * 512 + k];
  __syncthreads();
  for (int j = tid; j < 512; j += 256) {
    const float* w = ctx_w + (size_t)j * 512;
    float s0 = 0.f, s1 = 0.f, s2 = 0.f, s3 = 0.f;
    for (int k = 0; k < 512; k += 4) {
      float4 w4 = *(const float4*)(w + k);
      s0 = fmaf(hs[k], w4.x, s0);
      s1 = fmaf(hs[k + 1], w4.y, s1);
      s2 = fmaf(hs[k + 2], w4.z, s2);
      s3 = fmaf(hs[k + 3], w4.w, s3);
    }
    ctx[b * 512 + j] = ctx_b[j] + ((s0 + s1) + (s2 + s3));
  }
}

// ============================================================================
// fp32 -> bf16 (RNE), 4 elems/thread.
// ============================================================================
__global__ __launch_bounds__(256) void k_f2b(
    const float* __restrict__ in, unsigned short* __restrict__ out, int n)
{
  int i = (blockIdx.x * 256 + threadIdx.x) * 4;
  if (i < n) {
    float4 v = *(const float4*)(in + i);
    unsigned lo = (unsigned)f2b(v.x) | ((unsigned)f2b(v.y) << 16);
    unsigned hi = (unsigned)f2b(v.z) | ((unsigned)f2b(v.w) << 16);
    *(uint2*)(out + i) = make_uint2(lo, hi);
  }
}

// ============================================================================
// Zero helpers (ws poisoned to 0xAA before timing; re-init every call).
// ============================================================================
__global__ __launch_bounds__(64) void k_zero(int* __restrict__ p) {
  p[threadIdx.x] = 0;
}
__global__ __launch_bounds__(256) void k_zero_f(float* __restrict__ p) {
  p[blockIdx.x * 256 + threadIdx.x] = 0.f;
}

// ============================================================================
// Stage 3a: A[(t*64+b)][k] = bf16(tok_emb[tok][k] + ctx[b][k])
// ============================================================================
__global__ __launch_bounds__(128) void k_build_A(
    const float* __restrict__ tok_emb, const int* __restrict__ tgt,
    const float* __restrict__ ctx, unsigned short* __restrict__ A)
{
  const int r = blockIdx.x;
  const int t = r >> 6, b = r & 63;
  const int tok = (t == 0) ? 4096 : tgt[b * 50 + (t - 1)];
  const int i = threadIdx.x * 4;
  float4 ev = *(const float4*)(tok_emb + (size_t)tok * 512 + i);
  float4 cv = *(const float4*)(ctx + b * 512 + i);
  unsigned lo = (unsigned)f2b(ev.x + cv.x) | ((unsigned)f2b(ev.y + cv.y) << 16);
  unsigned hi = (unsigned)f2b(ev.z + cv.z) | ((unsigned)f2b(ev.w + cv.w) << 16);
  *(uint2*)(A + (size_t)r * 512 + i) = make_uint2(lo, hi);
}

// ============================================================================
// bf16 MFMA GEMM (m97 structure): C(MxN) = A(Mx512) @ B(Nx512)^T + bias.
// MODE 0: xgates; C TRANSPOSED (t, gate-dd, b) = (50,2048,64).
// MODE 1: head; C remapped (t*64+b, v) -> (b*50+t, v).
// ============================================================================
template <int MODE>
__global__ __launch_bounds__(256) void k_gemm_mfma(
    const unsigned short* __restrict__ A, const unsigned short* __restrict__ B,
    const float* __restrict__ bias_a, const float* __restrict__ bias_b,
    float* __restrict__ C, int NB)
{
  __shared__ unsigned short sA[128 * 32];
  __shared__ unsigned short sB[128 * 32];
  const int tid = threadIdx.x;
  const int bx = blockIdx.x % NB, by = blockIdx.x / NB;
  const int lane = tid & 63, wv = tid >> 6;
  const int wr = wv >> 1, wc = wv & 1;
  const unsigned short* Ab = A + (size_t)by * 128 * 512;
  const unsigned short* Bb = B + (size_t)bx * 128 * 512;

  f32x4 acc[4][4];
#pragma unroll
  for (int m = 0; m < 4; m++)
#pragma unroll
    for (int n = 0; n < 4; n++) acc[m][n] = (f32x4){0.f, 0.f, 0.f, 0.f};

  const int r0 = tid >> 2, c0 = (tid & 3) * 8;
  const int idx1 = tid + 256;
  const int r1 = idx1 >> 2, c1 = (idx1 & 3) * 8;
  unsigned short* lA0 = sA + (size_t)wv * 512;
  unsigned short* lA1 = sA + 2048 + (size_t)wv * 512;
  unsigned short* lB0 = sB + (size_t)wv * 512;
  unsigned short* lB1 = sB + 2048 + (size_t)wv * 512;

  const int frow = lane & 15;
  const int foff = (lane >> 4) * 8;

  for (int kc = 0; kc < 512; kc += 32) {
    gload16(Ab + (size_t)r0 * 512 + kc + c0, lA0);
    gload16(Ab + (size_t)r1 * 512 + kc + c1, lA1);
    gload16(Bb + (size_t)r0 * 512 + kc + c0, lB0);
    gload16(Bb + (size_t)r1 * 512 + kc + c1, lB1);
    __syncthreads();

    bf16x8 af[4], bfr[4];
#pragma unroll
    for (int m = 0; m < 4; m++)
      af[m] = *(const bf16x8*)(sA + (wr * 64 + m * 16 + frow) * 32 + foff);
#pragma unroll
    for (int n = 0; n < 4; n++)
      bfr[n] = *(const bf16x8*)(sB + (wc * 64 + n * 16 + frow) * 32 + foff);
#pragma unroll
    for (int m = 0; m < 4; m++)
#pragma unroll
      for (int n = 0; n < 4; n++)
        acc[m][n] = __builtin_amdgcn_mfma_f32_16x16x32_bf16(
            af[m], bfr[n], acc[m][n], 0, 0, 0);
    __syncthreads();
  }

  // C/D layout (m91-verified): col = lane&15, row = (lane>>4)*4 + j
#pragma unroll
  for (int n = 0; n < 4; n++) {
    const int gc = bx * 128 + wc * 64 + n * 16 + (lane & 15);
    const float bv = (MODE == 0) ? (bias_a[gc] + bias_b[gc]) : bias_a[gc];
#pragma unroll
    for (int m = 0; m < 4; m++) {
      const int rb = by * 128 + wr * 64 + m * 16 + (lane >> 4) * 4;
#pragma unroll
      for (int j = 0; j < 4; j++) {
        const int r = rb + j;
        float v = acc[m][n][j] + bv;
        int t = r >> 6, bb = r & 63;
        if (MODE == 0) {
          C[(size_t)t * 131072 + (size_t)gc * 64 + bb] = v;
        } else {
          C[((size_t)bb * 50 + t) * 4096 + gc] = v;
        }
      }
    }
  }
}

// ============================================================================
// Stage 4 (primary): PERSISTENT MFMA LSTM, one cooperative dispatch, 32 blocks.
// Round-6 lesson: per-fragment agent-atomic loads (2.1M uncoalesced ops/step
// @ ~15.6ns) were the 33us/step cost. Now: per step, the block stages the
// full H (hi+lo, 128 KB) into LDS with COALESCED coherent loads
// (global_load_dwordx4 sc0 sc1 = L1/L2 bypass, same coherence point the
// round-6 atomics proved correct), then MFMA reads fragments from LDS with an
// XOR swizzle (G4). h stores remain relaxed agent atomics (2/thread, proven).
// ============================================================================
__global__ __launch_bounds__(256, 1) void k_lstm_mfma(
    const float* __restrict__ xgT,            // (50,2048,64) xgates (biased)
    const float* __restrict__ w_hh,           // (2048,512) fp32
    const unsigned short* __restrict__ h0b,   // (64,512) bf16 hi
    const unsigned short* __restrict__ h0lo,  // (64,512) bf16 lo
    unsigned short* __restrict__ hallb,       // (50,64,512) bf16 hi history
    unsigned short* __restrict__ hlo,         // (2,64,512) bf16 lo ping-pong
    int* __restrict__ cnt)                    // >= 50 ints, zeroed
{
  __shared__ unsigned short s_hhi[64 * 512];  // 64 KB, swizzled rows
  __shared__ unsigned short s_hlo[64 * 512];  // 64 KB
  __shared__ float s_g[4][64][17];            // [gate][batch][dd_rel], 17.4 KB
  const int tid = threadIdx.x;
  const int kb = blockIdx.x;        // dims [16*kb, 16*kb+16)
  const int g = tid >> 6;           // gate = wave
  const int lane = tid & 63;
  const int frow = lane & 15;
  const int foff = (lane >> 4) * 8;

  // Load weight fragments once: w = w_hi + w_lo (bf16 split).
  bf16x8 whi[16], wlo[16];
  {
    const float* wrow = w_hh + (size_t)(g * 512 + kb * 16 + frow) * 512;
#pragma unroll
    for (int kf = 0; kf < 16; kf++) {
      float tmp[8];
      *(float4*)tmp = *(const float4*)(wrow + kf * 32 + foff);
      *(float4*)(tmp + 4) = *(const float4*)(wrow + kf * 32 + foff + 4);
#pragma unroll
      for (int j = 0; j < 8; j++) {
        unsigned short h = f2b(tmp[j]);
        whi[kf][j] = (short)h;
        wlo[kf][j] =
            (short)f2b(tmp[j] - __builtin_bit_cast(float, (unsigned)h << 16));
      }
    }
  }

  float c[4] = {0.f, 0.f, 0.f, 0.f};  // cell state: (dd = kb*16+dd2*4+i, b2)
  const int b2 = tid & 63, dd2 = tid >> 6;

  for (int t = 0; t < 50; ++t) {
    const unsigned short* Hhi = t ? hallb + (size_t)(t - 1) * 32768 : h0b;
    const unsigned short* Hlo = t ? hlo + (size_t)((t - 1) & 1) * 32768 : h0lo;

    // ---- Stage H (hi+lo) -> LDS: coalesced coherent 16B loads, 8 in flight.
#pragma unroll
    for (int half = 0; half < 2; half++) {
      const char* src = (const char*)(half ? Hlo : Hhi);
      char* dst = (char*)(half ? s_hlo : s_hhi);
#pragma unroll
      for (int bt = 0; bt < 2; bt++) {
        u32x4 r[8];
#pragma unroll
        for (int i = 0; i < 8; i++)
          cload16(src + (size_t)(tid + (bt * 8 + i) * 256) * 16, &r[i]);
        asm volatile("s_waitcnt vmcnt(0)" ::: "memory");
        __builtin_amdgcn_sched_barrier(0);
#pragma unroll
        for (int i = 0; i < 8; i++) {
          int byte = (tid + (bt * 8 + i) * 256) * 16;
          int swz = byte ^ (((byte >> 10) & 7) << 4);
          *(u32x4*)(dst + swz) = r[i];
        }
      }
    }
    __syncthreads();

    // ---- MFMA from LDS (XOR-swizzled fragment reads).
    f32x4 acc[4];
#pragma unroll
    for (int mt = 0; mt < 4; mt++) acc[mt] = (f32x4){0.f, 0.f, 0.f, 0.f};
#pragma unroll
    for (int kf = 0; kf < 16; kf++) {
#pragma unroll
      for (int mt = 0; mt < 4; mt++) {
        const int row = mt * 16 + frow;
        const int byte = (row << 10) + kf * 64 + foff * 2;
        const int swz = byte ^ ((row & 7) << 4);
        bf16x8 ah = *(const bf16x8*)((const char*)s_hhi + swz);
        bf16x8 al = *(const bf16x8*)((const char*)s_hlo + swz);
        acc[mt] = __builtin_amdgcn_mfma_f32_16x16x32_bf16(ah, whi[kf], acc[mt], 0, 0, 0);
        acc[mt] = __builtin_amdgcn_mfma_f32_16x16x32_bf16(ah, wlo[kf], acc[mt], 0, 0, 0);
        acc[mt] = __builtin_amdgcn_mfma_f32_16x16x32_bf16(al, whi[kf], acc[mt], 0, 0, 0);
      }
    }
    // C/D: col = lane&15 (dd_rel), row = (lane>>4)*4 + j (batch)
#pragma unroll
    for (int mt = 0; mt < 4; mt++)
#pragma unroll
      for (int j = 0; j < 4; j++)
        s_g[g][mt * 16 + (lane >> 4) * 4 + j][frow] = acc[mt][j];
    __syncthreads();

    // ---- c/h update: thread owns 4 cells (dd = kb*16 + dd2*4 + i, batch b2).
    const float* xr =
        xgT + (size_t)t * 131072 + (size_t)(kb * 16 + dd2 * 4) * 64 + b2;
    unsigned long long qh = 0, ql = 0;
#pragma unroll
    for (int i = 0; i < 4; i++) {
      float gi = s_g[0][b2][dd2 * 4 + i] + xr[(size_t)(0 * 512 + i) * 64];
      float gf = s_g[1][b2][dd2 * 4 + i] + xr[(size_t)(1 * 512 + i) * 64];
      float gg = s_g[2][b2][dd2 * 4 + i] + xr[(size_t)(2 * 512 + i) * 64];
      float go = s_g[3][b2][dd2 * 4 + i] + xr[(size_t)(3 * 512 + i) * 64];
      float ig = 1.f / (1.f + expf(-gi));
      float fg = 1.f / (1.f + expf(-gf));
      float og = 1.f / (1.f + expf(-go));
      float gt = tanhf(gg);
      c[i] = fmaf(fg, c[i], ig * gt);
      float h = og * tanhf(c[i]);
      unsigned short hh = f2b(h);
      unsigned short hl =
          f2b(h - __builtin_bit_cast(float, (unsigned)hh << 16));
      qh |= (unsigned long long)hh << (16 * i);
      ql |= (unsigned long long)hl << (16 * i);
    }
    const size_t ho = (size_t)b2 * 512 + kb * 16 + dd2 * 4;
    __hip_atomic_store((unsigned long long*)(hallb + (size_t)t * 32768 + ho),
                       qh, __ATOMIC_RELAXED, __HIP_MEMORY_SCOPE_AGENT);
    __hip_atomic_store(
        (unsigned long long*)(hlo + (size_t)(t & 1) * 32768 + ho), ql,
        __ATOMIC_RELAXED, __HIP_MEMORY_SCOPE_AGENT);
    __syncthreads();  // drains vmcnt(0) on every wave -> stores visible
    if (tid == 0) {
      __hip_atomic_fetch_add(&cnt[t], 1, __ATOMIC_RELAXED,
                             __HIP_MEMORY_SCOPE_AGENT);
      while (__hip_atomic_load(&cnt[t], __ATOMIC_RELAXED,
                               __HIP_MEMORY_SCOPE_AGENT) < LSTM_NB) {
        __builtin_amdgcn_s_sleep(1);
      }
    }
    __syncthreads();
  }
}

// ============================================================================
// Stage 4 (fallback): one LSTM step per launch (hang-proof). Used only if the
// cooperative launch is rejected.
// ============================================================================
__global__ __launch_bounds__(256) void k_lstm_step1(
    const float* __restrict__ xgT, const float* __restrict__ w_hh,
    const float* __restrict__ hin, float* __restrict__ hout,
    unsigned short* __restrict__ hallb_t, float* __restrict__ cbuf, int t)
{
  __shared__ float s_w[8][512];
  __shared__ float s_g[2][4][64];
  const int tid = threadIdx.x;
  const int dd0 = blockIdx.x * 2;

  for (int idx = tid; idx < 1024; idx += 256) {
    int row = idx >> 7;
    int k4 = (idx & 127) << 2;
    int q_ = row >> 1, dd_i = row & 1;
    *(float4*)&s_w[row][k4] =
        *(const float4*)(w_hh + (size_t)(q_ * 512 + dd0 + dd_i) * 512 + k4);
  }
  const int b = tid & 63;
  const int q = tid >> 6;
  __syncthreads();

  const float* hc = hin + b * 512;
  const float* xr = xgT + (size_t)t * 131072 + (size_t)(q * 512 + dd0) * 64 + b;
  float a0 = xr[0], a1 = xr[64];
  const float* w0 = s_w[q * 2 + 0];
  const float* w1 = s_w[q * 2 + 1];
#pragma unroll 8
  for (int k = 0; k < 512; k += 4) {
    float4 h4 = *(const float4*)(hc + k);
    float4 u = *(const float4*)(w0 + k);
    float4 v = *(const float4*)(w1 + k);
    a0 = fmaf(h4.x, u.x, fmaf(h4.y, u.y, fmaf(h4.z, u.z, fmaf(h4.w, u.w, a0))));
    a1 = fmaf(h4.x, v.x, fmaf(h4.y, v.y, fmaf(h4.z, v.z, fmaf(h4.w, v.w, a1))));
  }
  s_g[0][q][b] = a0;
  s_g[1][q][b] = a1;
  __syncthreads();
  if (q < 2) {
    const int dd = dd0 + q;
    float gi = s_g[q][0][b], gf = s_g[q][1][b];
    float gg = s_g[q][2][b], go = s_g[q][3][b];
    float ig = 1.f / (1.f + expf(-gi));
    float fg = 1.f / (1.f + expf(-gf));
    float og = 1.f / (1.f + expf(-go));
    float gt = tanhf(gg);
    float c = fmaf(fg, cbuf[b * 512 + dd], ig * gt);
    float h = og * tanhf(c);
    cbuf[b * 512 + dd] = c;
    hout[b * 512 + dd] = h;
    hallb_t[(size_t)b * 512 + dd] = f2b(h);
  }
}

// ============================================================================
extern "C" void kernel_launch(void* const* d_in, const int* in_sizes, int n_in,
                              void* d_out, int out_size, void* d_ws,
                              size_t ws_size, hipStream_t stream) {
  const float* mask   = (const float*)d_in[0];
  const int*   tgt    = (const int*)d_in[1];
  const float* w1     = (const float*)d_in[2];
  const float* b1     = (const float*)d_in[3];
  const float* w2     = (const float*)d_in[4];
  const float* b2     = (const float*)d_in[5];
  const float* feat_w = (const float*)d_in[6];
  const float* feat_b = (const float*)d_in[7];
  const float* ctx_w  = (const float*)d_in[8];
  const float* ctx_b  = (const float*)d_in[9];
  const float* temb   = (const float*)d_in[10];
  const float* w_ih   = (const float*)d_in[11];
  const float* w_hh_p = (const float*)d_in[12];
  const float* b_ih   = (const float*)d_in[13];
  const float* b_hh   = (const float*)d_in[14];
  const float* head_w = (const float*)d_in[15];
  const float* head_b = (const float*)d_in[16];

  float* ws = (float*)d_ws;
  // float-unit offsets; total 9,175,104 floats = 36.7 MB (< proven 39.85 MB)
  float* part  = ws;                       // [0, 65536)
  float* hbuf  = ws + 65536;               // [65536, 131072)  fp32 ping-pong
  float* ctx   = ws + 131072;              // [131072, 163840)
  int*   cnt   = (int*)(ws + 163840);      // [163840, 163904) 64 ints
  unsigned short* h0b  = (unsigned short*)(ws + 163904);    // 16384 fl
  unsigned short* h0lo = (unsigned short*)(ws + 180288);    // 16384 fl
  unsigned short* hlo  = (unsigned short*)(ws + 196672);    // 32768 fl
  unsigned short* Ab16 = (unsigned short*)(ws + 229440);    // 819200 fl
  unsigned short* hallb = Ab16;            // overlay: Ab16 dead after gemm<0>
  unsigned short* wihb = (unsigned short*)(ws + 1048640);   // 524288 fl
  unsigned short* hwb  = (unsigned short*)(ws + 1572928);   // 1048576 fl
  float* xgT   = ws + 2621504;             // 6553600 fl, ends 9175104
  float* cbuf  = part;                     // overlay: part dead after pool_h0
  float* out   = (float*)d_out;            // (64,50,4096)

  k_conv<<<2048, 512, 0, stream>>>(mask, w1, b1, w2, b2, part);
  k_f2b<<<1024, 256, 0, stream>>>(w_ih, wihb, 1048576);
  k_f2b<<<2048, 256, 0, stream>>>(head_w, hwb, 2097152);
  k_zero<<<1, 64, 0, stream>>>(cnt);
  k_pool_h0<<<64, 256, 0, stream>>>(part, feat_w, feat_b, hbuf, h0b, h0lo);
  k_ctx<<<64, 256, 0, stream>>>(hbuf, ctx_w, ctx_b, ctx);
  k_build_A<<<3200, 128, 0, stream>>>(temb, tgt, ctx, Ab16);
  k_gemm_mfma<0><<<25 * 16, 256, 0, stream>>>(Ab16, wihb, b_ih, b_hh, xgT, 16);

  // Persistent MFMA LSTM (cooperative -> co-residency guaranteed, hang-proof).
  {
    const float* xgT_c = xgT;
    const float* whh_c = w_hh_p;
    const unsigned short* h0b_c = h0b;
    const unsigned short* h0lo_c = h0lo;
    unsigned short* hallb_c = hallb;
    unsigned short* hlo_c = hlo;
    int* cnt_c = cnt;
    void* args[] = {(void*)&xgT_c,   (void*)&whh_c, (void*)&h0b_c,
                    (void*)&h0lo_c,  (void*)&hallb_c, (void*)&hlo_c,
                    (void*)&cnt_c};
    hipError_t e = hipLaunchCooperativeKernel(
        (const void*)k_lstm_mfma, dim3(LSTM_NB), dim3(256), args, 0, stream);
    if (e != hipSuccess) {
      (void)hipGetLastError();  // clear sticky error
      k_zero_f<<<128, 256, 0, stream>>>(cbuf);
      for (int t = 0; t < 50; t++) {
        const float* hin = hbuf + (t & 1) * 32768;
        float* hout = hbuf + ((t + 1) & 1) * 32768;
        k_lstm_step1<<<256, 256, 0, stream>>>(
            xgT, w_hh_p, hin, hout, hallb + (size_t)t * 32768, cbuf, t);
      }
    }
  }

  k_gemm_mfma<1><<<25 * 32, 256, 0, stream>>>(hallb, hwb, head_b, nullptr, out, 32);
}

// Round 8
// 568.298 us; speedup vs baseline: 4.0503x; 1.3764x over previous
//
#include <hip/hip_runtime.h>
#include <cmath>

typedef __attribute__((ext_vector_type(8))) _Float16 f16x8;
typedef __attribute__((ext_vector_type(4))) float f32x4;
typedef __attribute__((ext_vector_type(4))) unsigned u32x4;

#define LSTM_NB 32

__device__ __forceinline__ unsigned short f2h(float x) {
  return __builtin_bit_cast(unsigned short, (_Float16)x);
}

__device__ __forceinline__ void gload16(const void* g, void* l) {
  __builtin_amdgcn_global_load_lds(
      (const __attribute__((address_space(1))) void*)g,
      (__attribute__((address_space(3))) void*)l, 16, 0, 0);
}

// Coherent (cache-bypassing) coalesced 16B load — round-7-proven mechanism
// for reading same-dispatch agent-atomic stores.
__device__ __forceinline__ void cload16(const void* p, u32x4* dst) {
  asm volatile("global_load_dwordx4 %0, %1, off sc0 sc1"
               : "=v"(*dst)
               : "v"(p));
}

// ============================================================================
// Stage 1: fused conv1 + relu + maxpool2x2 + conv2 + relu + spatial-sum.
// Tile = 32x16 pooled px: LDS ~61 KB -> 2 blocks/CU. Grid 2048.
// ============================================================================
__global__ __launch_bounds__(512) void k_conv(
    const float* __restrict__ mask, const float* __restrict__ w1,
    const float* __restrict__ b1, const float* __restrict__ w2,
    const float* __restrict__ b2, float* __restrict__ part)
{
  __shared__ float s_p1[16][18 * 36];
  __shared__ float s_w1[144];
  __shared__ float s_b1[16];
  __shared__ float s_w2[4608];
  __shared__ float s_b2[32];

  const int tid = threadIdx.x;
  const int b = blockIdx.x >> 5;
  const int tile = blockIdx.x & 31;
  const int px0 = (tile & 3) * 32, py0 = (tile >> 2) * 16;
  const float* mb = mask + (size_t)b * 65536;

  for (int i = tid; i < 144; i += 512) s_w1[i] = w1[i];
  for (int i = tid; i < 4608; i += 512) s_w2[i] = w2[i];
  if (tid < 16) s_b1[tid] = b1[tid];
  if (tid < 32) s_b2[tid] = b2[tid];
  __syncthreads();

  for (int idx = tid; idx < 18 * 34; idx += 512) {
    int ly = idx / 34, lx = idx - ly * 34;
    int py = py0 - 1 + ly, px = px0 - 1 + lx;
    if (py < 0 || py >= 128 || px < 0 || px >= 128) {
      for (int o = 0; o < 16; o++) s_p1[o][ly * 36 + lx] = 0.f;
    } else {
      float patch[4][4];
      int gy0 = 2 * py - 1, gx0 = 2 * px - 1;
#pragma unroll
      for (int i = 0; i < 4; i++) {
        int gy = gy0 + i;
        bool yok = (gy >= 0 && gy < 256);
#pragma unroll
        for (int j = 0; j < 4; j++) {
          int gx = gx0 + j;
          patch[i][j] = (yok && gx >= 0 && gx < 256) ? mb[gy * 256 + gx] : 0.f;
        }
      }
      for (int o = 0; o < 16; o++) {
        float m = 0.f;
#pragma unroll
        for (int dy = 0; dy < 2; dy++)
#pragma unroll
          for (int dx = 0; dx < 2; dx++) {
            float v = s_b1[o];
#pragma unroll
            for (int ky = 0; ky < 3; ky++)
#pragma unroll
              for (int kx = 0; kx < 3; kx++)
                v = fmaf(patch[dy + ky][dx + kx], s_w1[o * 9 + ky * 3 + kx], v);
            m = fmaxf(m, v);
          }
        s_p1[o][ly * 36 + lx] = m;
      }
    }
  }
  __syncthreads();

  const int ocg = tid >> 6;
  const int sp = tid & 63;
  const int sx = (sp & 7) * 4, sy = (sp >> 3) * 2;
  float acc[4][8];
#pragma unroll
  for (int a = 0; a < 4; a++)
#pragma unroll
    for (int q = 0; q < 8; q++) acc[a][q] = 0.f;

  for (int ic = 0; ic < 16; ic++) {
    float p[4][6];
#pragma unroll
    for (int i = 0; i < 4; i++) {
      const float* row = &s_p1[ic][(sy + i) * 36 + sx];
#pragma unroll
      for (int j = 0; j < 6; j++) p[i][j] = row[j];
    }
#pragma unroll
    for (int o4 = 0; o4 < 4; o4++) {
      const int oc = ocg * 4 + o4;
      const float* w = &s_w2[(oc * 16 + ic) * 9];
      float w00 = w[0], w01 = w[1], w02 = w[2];
      float w10 = w[3], w11 = w[4], w12 = w[5];
      float w20 = w[6], w21 = w[7], w22 = w[8];
#pragma unroll
      for (int y = 0; y < 2; y++)
#pragma unroll
        for (int x = 0; x < 4; x++) {
          float s = acc[o4][y * 4 + x];
          s = fmaf(p[y][x], w00, s);
          s = fmaf(p[y][x + 1], w01, s);
          s = fmaf(p[y][x + 2], w02, s);
          s = fmaf(p[y + 1][x], w10, s);
          s = fmaf(p[y + 1][x + 1], w11, s);
          s = fmaf(p[y + 1][x + 2], w12, s);
          s = fmaf(p[y + 2][x], w20, s);
          s = fmaf(p[y + 2][x + 1], w21, s);
          s = fmaf(p[y + 2][x + 2], w22, s);
          acc[o4][y * 4 + x] = s;
        }
    }
  }

  const int lane = tid & 63;
#pragma unroll
  for (int o4 = 0; o4 < 4; o4++) {
    float bv = s_b2[ocg * 4 + o4];
    float s = 0.f;
#pragma unroll
    for (int q = 0; q < 8; q++) s += fmaxf(acc[o4][q] + bv, 0.f);
    for (int off = 32; off > 0; off >>= 1) s += __shfl_down(s, off, 64);
    if (lane == 0) part[(b * 32 + tile) * 32 + ocg * 4 + o4] = s;
  }
}

// ============================================================================
// Stage 2a: tile partials -> pooled mean -> h0 GEMM (K=32).
// Writes fp32 h0 (ctx + fallback) AND f16 h0 (persistent-MFMA LSTM).
// ============================================================================
__global__ __launch_bounds__(256) void k_pool_h0(
    const float* __restrict__ part, const float* __restrict__ feat_w,
    const float* __restrict__ feat_b, float* __restrict__ h0,
    unsigned short* __restrict__ h0f)
{
  const int b = blockIdx.x, tid = threadIdx.x;
  __shared__ float pl[32];
  if (tid < 32) {
    float s = 0.f;
    for (int t = 0; t < 32; t++) s += part[(b * 32 + t) * 32 + tid];
    pl[tid] = s * (1.0f / 16384.0f);
  }
  __syncthreads();
  for (int j = tid; j < 512; j += 256) {
    float acc = feat_b[j];
    const float* w = feat_w + j * 32;
#pragma unroll
    for (int ic = 0; ic < 32; ic++) acc = fmaf(pl[ic], w[ic], acc);
    h0[b * 512 + j] = acc;
    h0f[b * 512 + j] = f2h(acc);
  }
}

// ============================================================================
// Stage 2b: ctx = h0 @ ctx_w.T + ctx_b.
// ============================================================================
__global__ __launch_bounds__(256) void k_ctx(
    const float* __restrict__ h0, const float* __restrict__ ctx_w,
    const float* __restrict__ ctx_b, float* __restrict__ ctx)
{
  const int b = blockIdx.x, tid = threadIdx.x;
  __shared__ float hs[512];
  for (int k = tid; k < 512; k += 256) hs[k] = h0[b * 512 + k];
  __syncthreads();
  for (int j = tid; j < 512; j += 256) {
    const float* w = ctx_w + (size_t)j * 512;
    float s0 = 0.f, s1 = 0.f, s2 = 0.f, s3 = 0.f;
    for (int k = 0; k < 512; k += 4) {
      float4 w4 = *(const float4*)(w + k);
      s0 = fmaf(hs[k], w4.x, s0);
      s1 = fmaf(hs[k + 1], w4.y, s1);
      s2 = fmaf(hs[k + 2], w4.z, s2);
      s3 = fmaf(hs[k + 3], w4.w, s3);
    }
    ctx[b * 512 + j] = ctx_b[j] + ((s0 + s1) + (s2 + s3));
  }
}

// ============================================================================
// fp32 -> f16 (RNE), 4 elems/thread.
// ============================================================================
__global__ __launch_bounds__(256) void k_f2h(
    const float* __restrict__ in, unsigned short* __restrict__ out, int n)
{
  int i = (blockIdx.x * 256 + threadIdx.x) * 4;
  if (i < n) {
    float4 v = *(const float4*)(in + i);
    unsigned lo = (unsigned)f2h(v.x) | ((unsigned)f2h(v.y) << 16);
    unsigned hi = (unsigned)f2h(v.z) | ((unsigned)f2h(v.w) << 16);
    *(uint2*)(out + i) = make_uint2(lo, hi);
  }
}

// ============================================================================
// Zero helpers (ws poisoned to 0xAA before timing; re-init every call).
// ============================================================================
__global__ __launch_bounds__(64) void k_zero(int* __restrict__ p) {
  p[threadIdx.x] = 0;
}
__global__ __launch_bounds__(256) void k_zero_f(float* __restrict__ p) {
  p[blockIdx.x * 256 + threadIdx.x] = 0.f;
}

// ============================================================================
// Stage 3a: A[(t*64+b)][k] = f16(tok_emb[tok][k] + ctx[b][k])
// ============================================================================
__global__ __launch_bounds__(128) void k_build_A(
    const float* __restrict__ tok_emb, const int* __restrict__ tgt,
    const float* __restrict__ ctx, unsigned short* __restrict__ A)
{
  const int r = blockIdx.x;
  const int t = r >> 6, b = r & 63;
  const int tok = (t == 0) ? 4096 : tgt[b * 50 + (t - 1)];
  const int i = threadIdx.x * 4;
  float4 ev = *(const float4*)(tok_emb + (size_t)tok * 512 + i);
  float4 cv = *(const float4*)(ctx + b * 512 + i);
  unsigned lo = (unsigned)f2h(ev.x + cv.x) | ((unsigned)f2h(ev.y + cv.y) << 16);
  unsigned hi = (unsigned)f2h(ev.z + cv.z) | ((unsigned)f2h(ev.w + cv.w) << 16);
  *(uint2*)(A + (size_t)r * 512 + i) = make_uint2(lo, hi);
}

// ============================================================================
// f16 MFMA GEMM (m97 structure): C(MxN) = A(Mx512) @ B(Nx512)^T + bias.
// MODE 0: xgates; C TRANSPOSED (t, gate-dd, b) = (50,2048,64).
// MODE 1: head; C remapped (t*64+b, v) -> (b*50+t, v).
// ============================================================================
template <int MODE>
__global__ __launch_bounds__(256) void k_gemm_mfma(
    const unsigned short* __restrict__ A, const unsigned short* __restrict__ B,
    const float* __restrict__ bias_a, const float* __restrict__ bias_b,
    float* __restrict__ C, int NB)
{
  __shared__ unsigned short sA[128 * 32];
  __shared__ unsigned short sB[128 * 32];
  const int tid = threadIdx.x;
  const int bx = blockIdx.x % NB, by = blockIdx.x / NB;
  const int lane = tid & 63, wv = tid >> 6;
  const int wr = wv >> 1, wc = wv & 1;
  const unsigned short* Ab = A + (size_t)by * 128 * 512;
  const unsigned short* Bb = B + (size_t)bx * 128 * 512;

  f32x4 acc[4][4];
#pragma unroll
  for (int m = 0; m < 4; m++)
#pragma unroll
    for (int n = 0; n < 4; n++) acc[m][n] = (f32x4){0.f, 0.f, 0.f, 0.f};

  const int r0 = tid >> 2, c0 = (tid & 3) * 8;
  const int idx1 = tid + 256;
  const int r1 = idx1 >> 2, c1 = (idx1 & 3) * 8;
  unsigned short* lA0 = sA + (size_t)wv * 512;
  unsigned short* lA1 = sA + 2048 + (size_t)wv * 512;
  unsigned short* lB0 = sB + (size_t)wv * 512;
  unsigned short* lB1 = sB + 2048 + (size_t)wv * 512;

  const int frow = lane & 15;
  const int foff = (lane >> 4) * 8;

  for (int kc = 0; kc < 512; kc += 32) {
    gload16(Ab + (size_t)r0 * 512 + kc + c0, lA0);
    gload16(Ab + (size_t)r1 * 512 + kc + c1, lA1);
    gload16(Bb + (size_t)r0 * 512 + kc + c0, lB0);
    gload16(Bb + (size_t)r1 * 512 + kc + c1, lB1);
    __syncthreads();

    f16x8 af[4], bfr[4];
#pragma unroll
    for (int m = 0; m < 4; m++)
      af[m] = *(const f16x8*)(sA + (wr * 64 + m * 16 + frow) * 32 + foff);
#pragma unroll
    for (int n = 0; n < 4; n++)
      bfr[n] = *(const f16x8*)(sB + (wc * 64 + n * 16 + frow) * 32 + foff);
#pragma unroll
    for (int m = 0; m < 4; m++)
#pragma unroll
      for (int n = 0; n < 4; n++)
        acc[m][n] = __builtin_amdgcn_mfma_f32_16x16x32_f16(
            af[m], bfr[n], acc[m][n], 0, 0, 0);
    __syncthreads();
  }

  // C/D layout (m91-verified, dtype-independent): col=lane&15, row=(lane>>4)*4+j
#pragma unroll
  for (int n = 0; n < 4; n++) {
    const int gc = bx * 128 + wc * 64 + n * 16 + (lane & 15);
    const float bv = (MODE == 0) ? (bias_a[gc] + bias_b[gc]) : bias_a[gc];
#pragma unroll
    for (int m = 0; m < 4; m++) {
      const int rb = by * 128 + wr * 64 + m * 16 + (lane >> 4) * 4;
#pragma unroll
      for (int j = 0; j < 4; j++) {
        const int r = rb + j;
        float v = acc[m][n][j] + bv;
        int t = r >> 6, bb = r & 63;
        if (MODE == 0) {
          C[(size_t)t * 131072 + (size_t)gc * 64 + bb] = v;
        } else {
          C[((size_t)bb * 50 + t) * 4096 + gc] = v;
        }
      }
    }
  }
}

// ============================================================================
// Stage 4 (primary): PERSISTENT MFMA LSTM, one cooperative dispatch, 32 blocks.
// f16 datapath (round-8): single mfma_f32_16x16x32_f16 per fragment replaces
// the round-7 hi/lo bf16 triple -> staging halves (64 KB, ONE vmcnt round),
// LDS reads halve, weight VGPRs halve. The f16 h history (hallf) is both the
// head-GEMM A-operand and the recurrence source (no separate lo ping-pong).
// Coherence mechanism unchanged from round 7 (proven): coalesced sc0 sc1
// loads + relaxed agent-atomic stores + counter barrier, no fences.
// ============================================================================
__global__ __launch_bounds__(256, 1) void k_lstm_mfma(
    const float* __restrict__ xgT,            // (50,2048,64) xgates (biased)
    const float* __restrict__ w_hh,           // (2048,512) fp32
    const unsigned short* __restrict__ h0f,   // (64,512) f16
    unsigned short* __restrict__ hallf,       // (50,64,512) f16 h history
    int* __restrict__ cnt)                    // >= 50 ints, zeroed
{
  __shared__ unsigned short s_h[64 * 512];    // 64 KB, XOR-swizzled rows
  __shared__ float s_g[4][64][17];            // [gate][batch][dd_rel], 17.4 KB
  const int tid = threadIdx.x;
  const int kb = blockIdx.x;        // dims [16*kb, 16*kb+16)
  const int g = tid >> 6;           // gate = wave
  const int lane = tid & 63;
  const int frow = lane & 15;
  const int foff = (lane >> 4) * 8;

  // Load weight fragments once (f16): 16 frags = 64 VGPRs.
  f16x8 wf[16];
  {
    const float* wrow = w_hh + (size_t)(g * 512 + kb * 16 + frow) * 512;
#pragma unroll
    for (int kf = 0; kf < 16; kf++) {
      float tmp[8];
      *(float4*)tmp = *(const float4*)(wrow + kf * 32 + foff);
      *(float4*)(tmp + 4) = *(const float4*)(wrow + kf * 32 + foff + 4);
#pragma unroll
      for (int j = 0; j < 8; j++) wf[kf][j] = (_Float16)tmp[j];
    }
  }

  float c[4] = {0.f, 0.f, 0.f, 0.f};  // cell state: (dd = kb*16+dd2*4+i, b2)
  const int b2 = tid & 63, dd2 = tid >> 6;

  for (int t = 0; t < 50; ++t) {
    const unsigned short* H = t ? hallf + (size_t)(t - 1) * 32768 : h0f;

    // Prefetch this step's xgates (independent of h) — latency hides under
    // the staging wait.
    const float* xr =
        xgT + (size_t)t * 131072 + (size_t)(kb * 16 + dd2 * 4) * 64 + b2;
    float xv[16];
#pragma unroll
    for (int gq = 0; gq < 4; gq++)
#pragma unroll
      for (int i = 0; i < 4; i++)
        xv[gq * 4 + i] = xr[(size_t)(gq * 512 + i) * 64];

    // ---- Stage H -> LDS: 16 coalesced coherent 16B loads, one vmcnt round.
    {
      u32x4 r[16];
#pragma unroll
      for (int i = 0; i < 16; i++)
        cload16((const char*)H + (size_t)(tid + i * 256) * 16, &r[i]);
      asm volatile("s_waitcnt vmcnt(0)" ::: "memory");
      __builtin_amdgcn_sched_barrier(0);
#pragma unroll
      for (int i = 0; i < 16; i++) {
        int byte = (tid + i * 256) * 16;
        int swz = byte ^ (((byte >> 10) & 7) << 4);
        *(u32x4*)((char*)s_h + swz) = r[i];
      }
    }
    __syncthreads();

    // ---- MFMA from LDS (XOR-swizzled fragment reads), 64 MFMAs/wave.
    f32x4 acc[4];
#pragma unroll
    for (int mt = 0; mt < 4; mt++) acc[mt] = (f32x4){0.f, 0.f, 0.f, 0.f};
#pragma unroll
    for (int kf = 0; kf < 16; kf++) {
#pragma unroll
      for (int mt = 0; mt < 4; mt++) {
        const int row = mt * 16 + frow;
        const int byte = (row << 10) + kf * 64 + foff * 2;
        const int swz = byte ^ ((row & 7) << 4);
        f16x8 ah = *(const f16x8*)((const char*)s_h + swz);
        acc[mt] =
            __builtin_amdgcn_mfma_f32_16x16x32_f16(ah, wf[kf], acc[mt], 0, 0, 0);
      }
    }
    // C/D: col = lane&15 (dd_rel), row = (lane>>4)*4 + j (batch)
#pragma unroll
    for (int mt = 0; mt < 4; mt++)
#pragma unroll
      for (int j = 0; j < 4; j++)
        s_g[g][mt * 16 + (lane >> 4) * 4 + j][frow] = acc[mt][j];
    __syncthreads();

    // ---- c/h update: thread owns 4 cells (dd = kb*16 + dd2*4 + i, batch b2).
    unsigned long long qf = 0;
#pragma unroll
    for (int i = 0; i < 4; i++) {
      float gi = s_g[0][b2][dd2 * 4 + i] + xv[0 + i];
      float gf = s_g[1][b2][dd2 * 4 + i] + xv[4 + i];
      float gg = s_g[2][b2][dd2 * 4 + i] + xv[8 + i];
      float go = s_g[3][b2][dd2 * 4 + i] + xv[12 + i];
      float ig = 1.f / (1.f + expf(-gi));
      float fg = 1.f / (1.f + expf(-gf));
      float og = 1.f / (1.f + expf(-go));
      float gt = tanhf(gg);
      c[i] = fmaf(fg, c[i], ig * gt);
      float h = og * tanhf(c[i]);
      qf |= (unsigned long long)f2h(h) << (16 * i);
    }
    const size_t ho = (size_t)b2 * 512 + kb * 16 + dd2 * 4;
    __hip_atomic_store((unsigned long long*)(hallf + (size_t)t * 32768 + ho),
                       qf, __ATOMIC_RELAXED, __HIP_MEMORY_SCOPE_AGENT);
    __syncthreads();  // drains vmcnt(0) on every wave -> stores visible
    if (tid == 0) {
      __hip_atomic_fetch_add(&cnt[t], 1, __ATOMIC_RELAXED,
                             __HIP_MEMORY_SCOPE_AGENT);
      while (__hip_atomic_load(&cnt[t], __ATOMIC_RELAXED,
                               __HIP_MEMORY_SCOPE_AGENT) < LSTM_NB) {
        __builtin_amdgcn_s_sleep(1);
      }
    }
    __syncthreads();
  }
}

// ============================================================================
// Stage 4 (fallback): one LSTM step per launch (hang-proof). Used only if the
// cooperative launch is rejected.
// ============================================================================
__global__ __launch_bounds__(256) void k_lstm_step1(
    const float* __restrict__ xgT, const float* __restrict__ w_hh,
    const float* __restrict__ hin, float* __restrict__ hout,
    unsigned short* __restrict__ hallf_t, float* __restrict__ cbuf, int t)
{
  __shared__ float s_w[8][512];
  __shared__ float s_g[2][4][64];
  const int tid = threadIdx.x;
  const int dd0 = blockIdx.x * 2;

  for (int idx = tid; idx < 1024; idx += 256) {
    int row = idx >> 7;
    int k4 = (idx & 127) << 2;
    int q_ = row >> 1, dd_i = row & 1;
    *(float4*)&s_w[row][k4] =
        *(const float4*)(w_hh + (size_t)(q_ * 512 + dd0 + dd_i) * 512 + k4);
  }
  const int b = tid & 63;
  const int q = tid >> 6;
  __syncthreads();

  const float* hc = hin + b * 512;
  const float* xr = xgT + (size_t)t * 131072 + (size_t)(q * 512 + dd0) * 64 + b;
  float a0 = xr[0], a1 = xr[64];
  const float* w0 = s_w[q * 2 + 0];
  const float* w1 = s_w[q * 2 + 1];
#pragma unroll 8
  for (int k = 0; k < 512; k += 4) {
    float4 h4 = *(const float4*)(hc + k);
    float4 u = *(const float4*)(w0 + k);
    float4 v = *(const float4*)(w1 + k);
    a0 = fmaf(h4.x, u.x, fmaf(h4.y, u.y, fmaf(h4.z, u.z, fmaf(h4.w, u.w, a0))));
    a1 = fmaf(h4.x, v.x, fmaf(h4.y, v.y, fmaf(h4.z, v.z, fmaf(h4.w, v.w, a1))));
  }
  s_g[0][q][b] = a0;
  s_g[1][q][b] = a1;
  __syncthreads();
  if (q < 2) {
    const int dd = dd0 + q;
    float gi = s_g[q][0][b], gf = s_g[q][1][b];
    float gg = s_g[q][2][b], go = s_g[q][3][b];
    float ig = 1.f / (1.f + expf(-gi));
    float fg = 1.f / (1.f + expf(-gf));
    float og = 1.f / (1.f + expf(-go));
    float gt = tanhf(gg);
    float c = fmaf(fg, cbuf[b * 512 + dd], ig * gt);
    float h = og * tanhf(c);
    cbuf[b * 512 + dd] = c;
    hout[b * 512 + dd] = h;
    hallf_t[(size_t)b * 512 + dd] = f2h(h);
  }
}

// ============================================================================
extern "C" void kernel_launch(void* const* d_in, const int* in_sizes, int n_in,
                              void* d_out, int out_size, void* d_ws,
                              size_t ws_size, hipStream_t stream) {
  const float* mask   = (const float*)d_in[0];
  const int*   tgt    = (const int*)d_in[1];
  const float* w1     = (const float*)d_in[2];
  const float* b1     = (const float*)d_in[3];
  const float* w2     = (const float*)d_in[4];
  const float* b2     = (const float*)d_in[5];
  const float* feat_w = (const float*)d_in[6];
  const float* feat_b = (const float*)d_in[7];
  const float* ctx_w  = (const float*)d_in[8];
  const float* ctx_b  = (const float*)d_in[9];
  const float* temb   = (const float*)d_in[10];
  const float* w_ih   = (const float*)d_in[11];
  const float* w_hh_p = (const float*)d_in[12];
  const float* b_ih   = (const float*)d_in[13];
  const float* b_hh   = (const float*)d_in[14];
  const float* head_w = (const float*)d_in[15];
  const float* head_b = (const float*)d_in[16];

  float* ws = (float*)d_ws;
  // float-unit offsets; total 9,125,952 floats = 36.5 MB (< proven 39.85 MB)
  float* part  = ws;                       // [0, 65536)
  float* hbuf  = ws + 65536;               // [65536, 131072)  fp32 (fallback)
  float* ctx   = ws + 131072;              // [131072, 163840)
  int*   cnt   = (int*)(ws + 163840);      // [163840, 163904) 64 ints
  unsigned short* h0f  = (unsigned short*)(ws + 163904);    // 16384 fl
  unsigned short* Ab16 = (unsigned short*)(ws + 180288);    // 819200 fl
  unsigned short* hallf = Ab16;            // overlay: Ab16 dead after gemm<0>
  unsigned short* wihb = (unsigned short*)(ws + 999488);    // 524288 fl
  unsigned short* hwb  = (unsigned short*)(ws + 1523776);   // 1048576 fl
  float* xgT   = ws + 2572352;             // 6553600 fl, ends 9125952
  float* cbuf  = part;                     // overlay: part dead after pool_h0
  float* out   = (float*)d_out;            // (64,50,4096)

  k_conv<<<2048, 512, 0, stream>>>(mask, w1, b1, w2, b2, part);
  k_f2h<<<1024, 256, 0, stream>>>(w_ih, wihb, 1048576);
  k_f2h<<<2048, 256, 0, stream>>>(head_w, hwb, 2097152);
  k_zero<<<1, 64, 0, stream>>>(cnt);
  k_pool_h0<<<64, 256, 0, stream>>>(part, feat_w, feat_b, hbuf, h0f);
  k_ctx<<<64, 256, 0, stream>>>(hbuf, ctx_w, ctx_b, ctx);
  k_build_A<<<3200, 128, 0, stream>>>(temb, tgt, ctx, Ab16);
  k_gemm_mfma<0><<<25 * 16, 256, 0, stream>>>(Ab16, wihb, b_ih, b_hh, xgT, 16);

  // Persistent MFMA LSTM (cooperative -> co-residency guaranteed, hang-proof).
  {
    const float* xgT_c = xgT;
    const float* whh_c = w_hh_p;
    const unsigned short* h0f_c = h0f;
    unsigned short* hallf_c = hallf;
    int* cnt_c = cnt;
    void* args[] = {(void*)&xgT_c, (void*)&whh_c, (void*)&h0f_c,
                    (void*)&hallf_c, (void*)&cnt_c};
    hipError_t e = hipLaunchCooperativeKernel(
        (const void*)k_lstm_mfma, dim3(LSTM_NB), dim3(256), args, 0, stream);
    if (e != hipSuccess) {
      (void)hipGetLastError();  // clear sticky error
      k_zero_f<<<128, 256, 0, stream>>>(cbuf);
      for (int t = 0; t < 50; t++) {
        const float* hin = hbuf + (t & 1) * 32768;
        float* hout = hbuf + ((t + 1) & 1) * 32768;
        k_lstm_step1<<<256, 256, 0, stream>>>(
            xgT, w_hh_p, hin, hout, hallf + (size_t)t * 32768, cbuf, t);
      }
    }
  }

  k_gemm_mfma<1><<<25 * 32, 256, 0, stream>>>(hallf, hwb, head_b, nullptr, out, 32);
}